// Round 1
// 2103.155 us; speedup vs baseline: 1.1778x; 1.1778x over previous
//
#include <hip/hip_runtime.h>
#include <math.h>

using bf16   = __bf16;
using bf16x8 = __attribute__((ext_vector_type(8))) __bf16;
using f32x4  = __attribute__((ext_vector_type(4))) float;

typedef __attribute__((address_space(1))) const void* gc_ptr;
typedef __attribute__((address_space(3))) void*       ls_ptr;

#define MFMA16(a, b, c) __builtin_amdgcn_mfma_f32_16x16x32_bf16((a), (b), (c), 0, 0, 0)

// Runtime dtype detection: ln1_g[0] == 1.0f. fp32 -> 0x3F800000, bf16 pair -> 0x3F803F80.
__device__ __forceinline__ bool det_f32(const unsigned* det) { return *det == 0x3F800000u; }
__device__ __forceinline__ float ldx(const void* p, size_t i, bool f) {
    return f ? ((const float*)p)[i] : (float)(((const bf16*)p)[i]);
}

// ---------------------------------------------------------------------------
// Weight transpose: in (R x C, external dtype) -> out (C x R, bf16)
// ---------------------------------------------------------------------------
__global__ __launch_bounds__(256) void transpose2d(const void* __restrict__ in, size_t ioff,
                                                   bf16* __restrict__ out,
                                                   int R, int C, const unsigned* det)
{
    const bool f = det_f32(det);
    __shared__ bf16 t[32][33];
    int c0 = blockIdx.x * 32, r0 = blockIdx.y * 32;
    int tx = threadIdx.x, ty = threadIdx.y;
    #pragma unroll
    for (int i = ty; i < 32; i += 8)
        t[i][tx] = (bf16)ldx(in, ioff + (size_t)(r0 + i) * C + c0 + tx, f);
    __syncthreads();
    #pragma unroll
    for (int i = ty; i < 32; i += 8)
        out[(size_t)(c0 + i) * R + r0 + tx] = t[tx][i];
}

// ---------------------------------------------------------------------------
// LayerNorm over D=1024 (external-dtype x/g/b -> bf16 y). grid=rows, block=128.
// ---------------------------------------------------------------------------
__global__ __launch_bounds__(128) void ln_kernel(const void* __restrict__ x, size_t xoff,
                                                 const void* __restrict__ g,
                                                 const void* __restrict__ b,
                                                 bf16* __restrict__ y, const unsigned* det)
{
    const bool f = det_f32(det);
    int row = blockIdx.x, tid = threadIdx.x;
    float fv[8], s = 0.f, sq = 0.f;
    if (f) {
        const float* xp = (const float*)x + xoff + (size_t)row * 1024 + tid * 8;
        float4 a = *(const float4*)xp;
        float4 c = *(const float4*)(xp + 4);
        fv[0] = a.x; fv[1] = a.y; fv[2] = a.z; fv[3] = a.w;
        fv[4] = c.x; fv[5] = c.y; fv[6] = c.z; fv[7] = c.w;
    } else {
        bf16x8 xv = *(const bf16x8*)((const bf16*)x + xoff + (size_t)row * 1024 + tid * 8);
        #pragma unroll
        for (int j = 0; j < 8; ++j) fv[j] = (float)xv[j];
    }
    #pragma unroll
    for (int j = 0; j < 8; ++j) { s += fv[j]; sq += fv[j] * fv[j]; }
    #pragma unroll
    for (int d = 1; d < 64; d <<= 1) { s += __shfl_xor(s, d, 64); sq += __shfl_xor(sq, d, 64); }
    __shared__ float ss[2], sq2[2];
    int w = tid >> 6;
    if ((tid & 63) == 0) { ss[w] = s; sq2[w] = sq; }
    __syncthreads();
    s = ss[0] + ss[1]; sq = sq2[0] + sq2[1];
    float mean = s * (1.f / 1024.f);
    float var  = sq * (1.f / 1024.f) - mean * mean;
    float rstd = rsqrtf(var + 1e-5f);
    bf16x8 o;
    #pragma unroll
    for (int j = 0; j < 8; ++j)
        o[j] = (bf16)((fv[j] - mean) * rstd * ldx(g, tid * 8 + j, f) + ldx(b, tid * 8 + j, f));
    *(bf16x8*)(y + (size_t)row * 1024 + tid * 8) = o;
}

// ---------------------------------------------------------------------------
// OLD 128x128 GEMM, kept ONLY for EPI 3 (per-head transposed V write).
// ---------------------------------------------------------------------------
template <int EPI>
__global__ __launch_bounds__(256) void gemm_bt(const bf16* __restrict__ A,
                                               const bf16* __restrict__ BT,
                                               void* __restrict__ Cp, size_t coff,
                                               const void* __restrict__ bias, size_t boff,
                                               const void* __restrict__ resid, size_t roff,
                                               const void* __restrict__ coeffs, int ciR, int ciV,
                                               int M, int N, int K, const unsigned* det)
{
    const bool f = det_f32(det);
    __shared__ alignas(16) bf16 smem[17408];   // As(8192) + Bs(8192); EPI3 reuses as 128x136
    bf16* As = smem;
    bf16* Bs = smem + 8192;
    const int tid  = threadIdx.x;
    const int lane = tid & 63;
    const int w    = tid >> 6;
    const int wm   = w >> 1, wn = w & 1;
    const int quad = lane >> 4, l16 = lane & 15;
    const int bm = blockIdx.x * 128, bn = blockIdx.y * 128;

    f32x4 acc[4][4] = {};

    for (int k0 = 0; k0 < K; k0 += 64) {
        #pragma unroll
        for (int i = 0; i < 4; ++i) {
            int u = i * 256 + tid;
            int r = u >> 3, c = (u & 7) * 8;
            __builtin_amdgcn_global_load_lds((gc_ptr)(A + (size_t)(bm + r) * K + k0 + c),
                                             (ls_ptr)(As + (size_t)(i * 256 + (tid & 192)) * 8),
                                             16, 0, 0);
        }
        #pragma unroll
        for (int i = 0; i < 4; ++i) {
            int u = i * 256 + tid;
            int r = u >> 3, c = (u & 7) * 8;
            __builtin_amdgcn_global_load_lds((gc_ptr)(BT + (size_t)(bn + r) * K + k0 + c),
                                             (ls_ptr)(Bs + (size_t)(i * 256 + (tid & 192)) * 8),
                                             16, 0, 0);
        }
        __syncthreads();
        #pragma unroll
        for (int kk = 0; kk < 2; ++kk) {
            bf16x8 af[4], bfr[4];
            #pragma unroll
            for (int i = 0; i < 4; ++i)
                af[i] = *(const bf16x8*)(As + (wm * 64 + i * 16 + l16) * 64 + kk * 32 + quad * 8);
            #pragma unroll
            for (int i = 0; i < 4; ++i)
                bfr[i] = *(const bf16x8*)(Bs + (wn * 64 + i * 16 + l16) * 64 + kk * 32 + quad * 8);
            #pragma unroll
            for (int im = 0; im < 4; ++im)
                #pragma unroll
                for (int in = 0; in < 4; ++in)
                    acc[im][in] = MFMA16(af[im], bfr[in], acc[im][in]);
        }
        __syncthreads();
    }

    if (EPI == 3) {
        // transpose through LDS: T[dk][n], stride 136 (16B-aligned rows)
        bf16* T = smem;
        #pragma unroll
        for (int in = 0; in < 4; ++in) {
            int dk = wn * 64 + in * 16 + l16;
            float bv = ldx(bias, boff + bn + dk, f);
            #pragma unroll
            for (int im = 0; im < 4; ++im)
                #pragma unroll
                for (int r = 0; r < 4; ++r) {
                    int n = wm * 64 + im * 16 + quad * 4 + r;
                    T[dk * 136 + n] = (bf16)(acc[im][in][r] + bv);
                }
        }
        __syncthreads();
        int bq = bm >> 8, n0 = bm & 255, h = bn >> 7;
        bf16* dst = (bf16*)Cp + ((size_t)(bq * 8 + h) * 128) * 256 + n0;
        #pragma unroll
        for (int it = 0; it < 8; ++it) {
            int idx = it * 256 + tid;
            int dk = idx >> 4, ch = idx & 15;
            *(bf16x8*)(dst + (size_t)dk * 256 + ch * 8) = *(const bf16x8*)(T + dk * 136 + ch * 8);
        }
        return;
    }

    float cR = 0.f, cV = 0.f;
    if (EPI == 2) { cR = ldx(coeffs, ciR, f); cV = ldx(coeffs, ciV, f); }
    #pragma unroll
    for (int in = 0; in < 4; ++in) {
        int col = bn + wn * 64 + in * 16 + l16;
        float bv = ldx(bias, boff + col, f);
        #pragma unroll
        for (int im = 0; im < 4; ++im) {
            #pragma unroll
            for (int r = 0; r < 4; ++r) {
                int row = bm + wm * 64 + im * 16 + quad * 4 + r;
                float v = acc[im][in][r] + bv;
                if (EPI == 1) v = 0.5f * v * (1.f + erff(v * 0.7071067811865476f));
                size_t o = coff + (size_t)row * N + col;
                if (EPI == 2) {
                    v = cR * ldx(resid, roff + (size_t)row * N + col, f) + cV * v;
                    if (f) ((float*)Cp)[o] = v; else ((bf16*)Cp)[o] = (bf16)v;
                } else {
                    ((bf16*)Cp)[o] = (bf16)v;
                }
            }
        }
    }
}

// ---------------------------------------------------------------------------
// NEW: 256x256-tile 8-phase GEMM (T2 swizzle + T3/T4 counted vmcnt + T5 setprio).
// 512 threads = 8 waves (2M x 4N), each wave owns a 128x64 output tile.
// BK=64; LDS = 2 buffers x (A 256x64 + B 256x64) bf16 = 128 KiB; 1 block/CU.
// Half-tiles are interleaved row-sets so each LDS region is fully read exactly
// one phase before its overwrite is issued:
//   A-lo = rows {0-63,128-191} (each wave's m0-3)   -> read complete after P1
//   B-hi = rows with bit5=1    (each wave's n2-3)   -> read complete after P2
//   A-hi = rows {64-127,192-255}                    -> read complete after P3
// Stage slots (tile t): P1: A-hi(t+1); P2: A-lo(t+2); P3: B-lo(t+2); P4: B-hi(t+2)
// -> 3 half-tiles (6 loads) in flight at each K-tile boundary: s_waitcnt vmcnt(6).
// LDS swizzle: LDS[r][c] holds src[r][c ^ ((r&7)*8)] (pre-swizzled global source,
// linear global_load_lds dest; reads XOR the same pattern) -> conflict-free b128.
// ---------------------------------------------------------------------------
template <int BS>
__device__ __forceinline__ void stage_h(const bf16* __restrict__ src, int Kd, bf16* dst,
                                        int h, int tid, size_t base)
{
    const int msk = (1 << BS) - 1;
    #pragma unroll
    for (int j = 0; j < 2; ++j) {
        int rl  = j * 64 + (tid >> 3);                                   // logical row 0..127
        int rp  = (rl & msk) + ((rl >> BS) << (BS + 1)) + (h << BS);     // physical row 0..255
        int rl0 = j * 64 + ((tid & 448) >> 3);                           // wave-uniform first row
        int rp0 = (rl0 & msk) + ((rl0 >> BS) << (BS + 1)) + (h << BS);
        int cs  = ((tid & 7) ^ ((tid >> 3) & 7)) << 3;                   // pre-swizzled source col
        __builtin_amdgcn_global_load_lds((gc_ptr)(src + base + (size_t)rp * Kd + cs),
                                         (ls_ptr)(dst + rp0 * 64), 16, 0, 0);
    }
}

#define BARR()  asm volatile("s_barrier" ::: "memory")
#define LGKM0() asm volatile("s_waitcnt lgkmcnt(0)" ::: "memory")

#define LD_AF(AB, MH)                                                                   \
    _Pragma("unroll") for (int m_ = 0; m_ < 4; ++m_)                                    \
    _Pragma("unroll") for (int kk_ = 0; kk_ < 2; ++kk_)                                 \
        af[m_][kk_] = *(const bf16x8*)((AB) + (wm * 128 + (MH) * 64 + m_ * 16 + l16) * 64 \
                                       + ((kk_ * 32 + quad * 8) ^ swzc));

#define LD_BF(BB, NH)                                                                   \
    _Pragma("unroll") for (int n_ = 0; n_ < 2; ++n_)                                    \
    _Pragma("unroll") for (int kk_ = 0; kk_ < 2; ++kk_)                                 \
        bff[(NH) * 2 + n_][kk_] = *(const bf16x8*)((BB) + (wn * 64 + (NH) * 32 + n_ * 16 + l16) * 64 \
                                                   + ((kk_ * 32 + quad * 8) ^ swzc));

#define MMQ(MH, NH)                                                                     \
    _Pragma("unroll") for (int m_ = 0; m_ < 4; ++m_)                                    \
    _Pragma("unroll") for (int n_ = 0; n_ < 2; ++n_)                                    \
    _Pragma("unroll") for (int kk_ = 0; kk_ < 2; ++kk_)                                 \
        acc[(MH) * 4 + m_][(NH) * 2 + n_] =                                             \
            MFMA16(af[m_][kk_], bff[(NH) * 2 + n_][kk_], acc[(MH) * 4 + m_][(NH) * 2 + n_]);

#define KTILE(P, T)                                                                     \
    {                                                                                   \
        const bf16* Ab = smem + (P) * 32768;                                            \
        const bf16* Bb = smem + (P) * 32768 + 16384;                                    \
        bf16* An = smem + (1 - (P)) * 32768;                                            \
        bf16* Ac = smem + (P) * 32768;                                                  \
        bf16* Bc = smem + (P) * 32768 + 16384;                                          \
        /* P1: af(mh=0)+bf(nh=0); stage A-hi(t+1) */                                    \
        LD_AF(Ab, 0)                                                                    \
        LD_BF(Bb, 0)                                                                    \
        if ((T) + 1 < NT) stage_h<6>(A, K, An, 1, tid, Arow + (size_t)((T) + 1) * 64);  \
        BARR(); LGKM0();                                                                \
        __builtin_amdgcn_s_setprio(1); MMQ(0, 0) __builtin_amdgcn_s_setprio(0);         \
        BARR();                                                                         \
        /* P2: bf(nh=1); stage A-lo(t+2) */                                             \
        LD_BF(Bb, 1)                                                                    \
        if ((T) + 2 < NT) stage_h<6>(A, K, Ac, 0, tid, Arow + (size_t)((T) + 2) * 64);  \
        BARR(); LGKM0();                                                                \
        __builtin_amdgcn_s_setprio(1); MMQ(0, 1) __builtin_amdgcn_s_setprio(0);         \
        BARR();                                                                         \
        /* P3: af(mh=1); stage B-lo(t+2) */                                             \
        LD_AF(Ab, 1)                                                                    \
        if ((T) + 2 < NT) stage_h<5>(BT, K, Bc, 0, tid, Brow + (size_t)((T) + 2) * 64); \
        BARR(); LGKM0();                                                                \
        __builtin_amdgcn_s_setprio(1); MMQ(1, 0) __builtin_amdgcn_s_setprio(0);         \
        BARR();                                                                         \
        /* P4: stage B-hi(t+2); counted vmcnt at K-tile boundary */                     \
        if ((T) + 2 < NT) stage_h<5>(BT, K, Bc, 1, tid, Brow + (size_t)((T) + 2) * 64); \
        BARR();                                                                         \
        __builtin_amdgcn_s_setprio(1); MMQ(1, 1) __builtin_amdgcn_s_setprio(0);         \
        if ((T) + 1 < NT) {                                                             \
            if ((T) + 2 < NT) { asm volatile("s_waitcnt vmcnt(6)" ::: "memory"); }      \
            else              { asm volatile("s_waitcnt vmcnt(0)" ::: "memory"); }      \
            BARR();                                                                     \
        }                                                                               \
    }

template <int EPI>
__global__ __launch_bounds__(512, 2) void gemm256(const bf16* __restrict__ A,
                                                  const bf16* __restrict__ BT,
                                                  void* __restrict__ Cp, size_t coff,
                                                  const void* __restrict__ bias, size_t boff,
                                                  const void* __restrict__ resid, size_t roff,
                                                  const void* __restrict__ coeffs, int ciR, int ciV,
                                                  int M, int N, int K, const unsigned* det)
{
    const bool f = det_f32(det);
    __shared__ alignas(16) bf16 smem[65536];   // 128 KiB: 2 x (A 16384 + B 16384) elems

    // bijective XCD swizzle (nwg % 8 == 0 for all our grids), N-major decomposition
    const int nwg = gridDim.x;
    const int cpx = nwg >> 3;
    const int bid = blockIdx.x;
    const int swz = (bid & 7) * cpx + (bid >> 3);
    const int nbx = M >> 8;
    const int bx = swz % nbx, by = swz / nbx;
    const int bm = bx << 8, bn = by << 8;

    const int tid  = threadIdx.x;
    const int lane = tid & 63, w = tid >> 6;
    const int wm = w >> 2, wn = w & 3;
    const int quad = lane >> 4, l16 = lane & 15;
    const int swzc = (l16 & 7) << 3;

    const int NT = K >> 6;
    const size_t Arow = (size_t)bm * K;
    const size_t Brow = (size_t)bn * K;

    f32x4 acc[8][4] = {};
    bf16x8 af[4][2], bff[4][2];

    // prologue: tile0 (all 4 halves) + tile1 (A-lo, B-lo, B-hi) -> 14 loads, keep 6 in flight
    stage_h<6>(A,  K, smem,         0, tid, Arow);
    stage_h<6>(A,  K, smem,         1, tid, Arow);
    stage_h<5>(BT, K, smem + 16384, 0, tid, Brow);
    stage_h<5>(BT, K, smem + 16384, 1, tid, Brow);
    stage_h<6>(A,  K, smem + 32768, 0, tid, Arow + 64);
    stage_h<5>(BT, K, smem + 49152, 0, tid, Brow + 64);
    stage_h<5>(BT, K, smem + 49152, 1, tid, Brow + 64);
    asm volatile("s_waitcnt vmcnt(6)" ::: "memory");
    BARR();

    for (int t = 0; t < NT; t += 2) {   // NT is even for all our shapes (16 or 64)
        KTILE(0, t)
        KTILE(1, t + 1)
    }

    // epilogue (no LDS use; no barrier needed)
    float cR = 0.f, cV = 0.f;
    if (EPI == 2) { cR = ldx(coeffs, ciR, f); cV = ldx(coeffs, ciV, f); }
    #pragma unroll
    for (int n = 0; n < 4; ++n) {
        int col = bn + wn * 64 + n * 16 + l16;
        float bv = ldx(bias, boff + col, f);
        #pragma unroll
        for (int m = 0; m < 8; ++m) {
            #pragma unroll
            for (int r = 0; r < 4; ++r) {
                int row = bm + wm * 128 + m * 16 + quad * 4 + r;
                float v = acc[m][n][r] + bv;
                if (EPI == 1) v = 0.5f * v * (1.f + erff(v * 0.7071067811865476f));
                size_t o = coff + (size_t)row * N + col;
                if (EPI == 2) {
                    v = cR * ldx(resid, roff + (size_t)row * N + col, f) + cV * v;
                    if (f) ((float*)Cp)[o] = v; else ((bf16*)Cp)[o] = (bf16)v;
                } else {
                    ((bf16*)Cp)[o] = (bf16)v;
                }
            }
        }
    }
}

// ---------------------------------------------------------------------------
// Cross-attention, one stream: grid 2048 = 64 b x 8 h x 4 row-blocks of 64.
// ---------------------------------------------------------------------------
__global__ __launch_bounds__(256) void attn_kernel(const bf16* __restrict__ Q,
                                                   const bf16* __restrict__ K,
                                                   const bf16* __restrict__ VT,
                                                   bf16* __restrict__ O)
{
    const int bi = blockIdx.x;
    const int mb = bi & 3, h = (bi >> 2) & 7, b = bi >> 5;
    const bf16* Qp = Q + (size_t)b * (256 * 1024) + h * 128;
    const bf16* Kp = K + (size_t)b * (256 * 1024) + h * 128;
    const bf16* Vp = VT + (size_t)(b * 8 + h) * (128 * 256);
    bf16* Op = O + (size_t)b * (256 * 1024) + h * 128;
    const int m0 = mb * 64;

    const int tid = threadIdx.x, lane = tid & 63, w = tid >> 6;
    const int quad = lane >> 4, l16 = lane & 15;

    f32x4 sa[4][4] = {};
    #pragma unroll
    for (int k0 = 0; k0 < 128; k0 += 32) {
        bf16x8 aq[4], bk[4];
        #pragma unroll
        for (int i = 0; i < 4; ++i)
            aq[i] = *(const bf16x8*)(Qp + (size_t)(m0 + i * 16 + l16) * 1024 + k0 + quad * 8);
        #pragma unroll
        for (int i = 0; i < 4; ++i)
            bk[i] = *(const bf16x8*)(Kp + (size_t)(w * 64 + i * 16 + l16) * 1024 + k0 + quad * 8);
        #pragma unroll
        for (int im = 0; im < 4; ++im)
            #pragma unroll
            for (int in = 0; in < 4; ++in)
                sa[im][in] = MFMA16(aq[im], bk[in], sa[im][in]);
    }
    const float scale = 0.088388347648318447f;  // 1/sqrt(128)
    #pragma unroll
    for (int im = 0; im < 4; ++im)
        #pragma unroll
        for (int in = 0; in < 4; ++in)
            #pragma unroll
            for (int r = 0; r < 4; ++r)
                sa[im][in][r] *= scale;

    __shared__ float red1[4][64];
    __shared__ float red2[4][64];
    __shared__ alignas(16) bf16 Ps[64 * 264];

    float rmax[4][4];
    #pragma unroll
    for (int im = 0; im < 4; ++im)
        #pragma unroll
        for (int r = 0; r < 4; ++r) {
            float m = fmaxf(fmaxf(sa[im][0][r], sa[im][1][r]), fmaxf(sa[im][2][r], sa[im][3][r]));
            #pragma unroll
            for (int d = 1; d < 16; d <<= 1) m = fmaxf(m, __shfl_xor(m, d, 64));
            rmax[im][r] = m;
        }
    if (l16 == 0)
        #pragma unroll
        for (int im = 0; im < 4; ++im)
            #pragma unroll
            for (int r = 0; r < 4; ++r)
                red1[w][im * 16 + quad * 4 + r] = rmax[im][r];
    __syncthreads();
    #pragma unroll
    for (int im = 0; im < 4; ++im)
        #pragma unroll
        for (int r = 0; r < 4; ++r) {
            int row = im * 16 + quad * 4 + r;
            rmax[im][r] = fmaxf(fmaxf(red1[0][row], red1[1][row]),
                                fmaxf(red1[2][row], red1[3][row]));
        }

    float rsum[4][4];
    #pragma unroll
    for (int im = 0; im < 4; ++im)
        #pragma unroll
        for (int r = 0; r < 4; ++r) {
            float t = 0.f;
            #pragma unroll
            for (int in = 0; in < 4; ++in) {
                float e = __expf(sa[im][in][r] - rmax[im][r]);
                sa[im][in][r] = e;
                t += e;
            }
            #pragma unroll
            for (int d = 1; d < 16; d <<= 1) t += __shfl_xor(t, d, 64);
            rsum[im][r] = t;
        }
    if (l16 == 0)
        #pragma unroll
        for (int im = 0; im < 4; ++im)
            #pragma unroll
            for (int r = 0; r < 4; ++r)
                red2[w][im * 16 + quad * 4 + r] = rsum[im][r];
    __syncthreads();
    #pragma unroll
    for (int im = 0; im < 4; ++im)
        #pragma unroll
        for (int r = 0; r < 4; ++r) {
            int row = im * 16 + quad * 4 + r;
            float inv = 1.f / (red2[0][row] + red2[1][row] + red2[2][row] + red2[3][row]);
            #pragma unroll
            for (int in = 0; in < 4; ++in)
                Ps[row * 264 + w * 64 + in * 16 + l16] = (bf16)(sa[im][in][r] * inv);
        }
    __syncthreads();

    f32x4 oa[4][2] = {};
    #pragma unroll
    for (int k0 = 0; k0 < 256; k0 += 32) {
        bf16x8 ap[4], bv[2];
        #pragma unroll
        for (int im = 0; im < 4; ++im)
            ap[im] = *(const bf16x8*)(Ps + (im * 16 + l16) * 264 + k0 + quad * 8);
        #pragma unroll
        for (int in = 0; in < 2; ++in)
            bv[in] = *(const bf16x8*)(Vp + (size_t)(w * 32 + in * 16 + l16) * 256 + k0 + quad * 8);
        #pragma unroll
        for (int im = 0; im < 4; ++im)
            #pragma unroll
            for (int in = 0; in < 2; ++in)
                oa[im][in] = MFMA16(ap[im], bv[in], oa[im][in]);
    }
    #pragma unroll
    for (int im = 0; im < 4; ++im)
        #pragma unroll
        for (int in = 0; in < 2; ++in)
            #pragma unroll
            for (int r = 0; r < 4; ++r) {
                int row = m0 + im * 16 + quad * 4 + r;
                int col = w * 32 + in * 16 + l16;
                Op[(size_t)row * 1024 + col] = (bf16)oa[im][in][r];
            }
}

// ---------------------------------------------------------------------------
extern "C" void kernel_launch(void* const* d_in, const int* in_sizes, int n_in,
                              void* d_out, int out_size, void* d_ws, size_t ws_size,
                              hipStream_t stream)
{
    const void* rgb    = d_in[0];
    const void* ir     = d_in[1];
    const void* ln1_g  = d_in[2];
    const void* ln1_b  = d_in[3];
    const void* ln2_g  = d_in[4];
    const void* ln2_b  = d_in[5];
    const void* Wqkv_v = d_in[6];
    const void* bqkv_v = d_in[7];
    const void* Wqkv_i = d_in[8];
    const void* bqkv_i = d_in[9];
    const void* Wo_v   = d_in[10];
    const void* bo_v   = d_in[11];
    const void* Wo_i   = d_in[12];
    const void* bo_i   = d_in[13];
    const void* bln_g  = d_in[14];
    const void* bln_b  = d_in[15];
    const void* W1_v   = d_in[16];
    const void* b1_v   = d_in[17];
    const void* W2_v   = d_in[18];
    const void* b2_v   = d_in[19];
    const void* W1_i   = d_in[20];
    const void* b1_i   = d_in[21];
    const void* W2_i   = d_in[22];
    const void* b2_i   = d_in[23];
    const void* coeffs = d_in[24];
    const unsigned* det = (const unsigned*)ln1_g;

    // workspace layout (bytes), peak 272,629,760 (~260 MiB)
    char* ws = (char*)d_ws;
    bf16* wtq_v  = (bf16*)(ws + 0);            // 6 MiB (3x 1024x1024)
    bf16* wtq_i  = (bf16*)(ws + 6291456);
    bf16* wto_v  = (bf16*)(ws + 12582912);     // 2 MiB
    bf16* wto_i  = (bf16*)(ws + 14680064);
    bf16* wt1_v  = (bf16*)(ws + 16777216);     // 8 MiB (4096x1024)
    bf16* wt1_i  = (bf16*)(ws + 25165824);
    bf16* wt2_v  = (bf16*)(ws + 33554432);     // 8 MiB (1024x4096)
    bf16* wt2_i  = (bf16*)(ws + 41943040);
    bf16* lnbuf  = (bf16*)(ws + 50331648);     // 32 MiB; reused as att_i
    bf16* q_v    = (bf16*)(ws + 83886080);     // 32 MiB; reused as att_v, then Hbuf
    bf16* k_v    = (bf16*)(ws + 117440512);
    bf16* vt_v   = (bf16*)(ws + 150994944);
    bf16* q_i    = (bf16*)(ws + 184549376);
    bf16* k_i    = (bf16*)(ws + 218103808);    // reused as mlp_ln
    bf16* vt_i   = (bf16*)(ws + 251658240);    // ends 285212672
    bf16* att_i  = lnbuf;
    bf16* att_v  = q_v;
    bf16* Hbuf   = (bf16*)(ws + 83886080);     // 128 MiB (16384x4096)
    bf16* mlp_ln = (bf16*)(ws + 218103808);

    dim3 tb(32, 8);
    // ---- weight transposes (external dtype -> bf16 N x K)
    for (int t = 0; t < 3; ++t) {
        transpose2d<<<dim3(32, 32), tb, 0, stream>>>(Wqkv_v, (size_t)t * 1048576, wtq_v + (size_t)t * 1048576, 1024, 1024, det);
        transpose2d<<<dim3(32, 32), tb, 0, stream>>>(Wqkv_i, (size_t)t * 1048576, wtq_i + (size_t)t * 1048576, 1024, 1024, det);
    }
    transpose2d<<<dim3(32, 32),  tb, 0, stream>>>(Wo_v, 0, wto_v, 1024, 1024, det);
    transpose2d<<<dim3(32, 32),  tb, 0, stream>>>(Wo_i, 0, wto_i, 1024, 1024, det);
    transpose2d<<<dim3(128, 32), tb, 0, stream>>>(W1_v, 0, wt1_v, 1024, 4096, det);
    transpose2d<<<dim3(128, 32), tb, 0, stream>>>(W1_i, 0, wt1_i, 1024, 4096, det);
    transpose2d<<<dim3(32, 128), tb, 0, stream>>>(W2_v, 0, wt2_v, 4096, 1024, det);
    transpose2d<<<dim3(32, 128), tb, 0, stream>>>(W2_i, 0, wt2_i, 4096, 1024, det);

    // ---- LN + QKV (Q,K via 256^2 8-phase; V via old EPI3 per-head transpose)
    ln_kernel<<<16384, 128, 0, stream>>>(rgb, 0, ln1_g, ln1_b, lnbuf, det);
    gemm256<0><<<256, 512, 0, stream>>>(lnbuf, wtq_v + 0 * 1048576, q_v, 0, bqkv_v, 0,    nullptr, 0, nullptr, 0, 0, 16384, 1024, 1024, det);
    gemm256<0><<<256, 512, 0, stream>>>(lnbuf, wtq_v + 1 * 1048576, k_v, 0, bqkv_v, 1024, nullptr, 0, nullptr, 0, 0, 16384, 1024, 1024, det);
    gemm_bt<3><<<dim3(128, 8), 256, 0, stream>>>(lnbuf, wtq_v + 2 * 1048576, vt_v, 0, bqkv_v, 2048, nullptr, 0, nullptr, 0, 0, 16384, 1024, 1024, det);
    ln_kernel<<<16384, 128, 0, stream>>>(ir, 0, ln2_g, ln2_b, lnbuf, det);
    gemm256<0><<<256, 512, 0, stream>>>(lnbuf, wtq_i + 0 * 1048576, q_i, 0, bqkv_i, 0,    nullptr, 0, nullptr, 0, 0, 16384, 1024, 1024, det);
    gemm256<0><<<256, 512, 0, stream>>>(lnbuf, wtq_i + 1 * 1048576, k_i, 0, bqkv_i, 1024, nullptr, 0, nullptr, 0, 0, 16384, 1024, 1024, det);
    gemm_bt<3><<<dim3(128, 8), 256, 0, stream>>>(lnbuf, wtq_i + 2 * 1048576, vt_i, 0, bqkv_i, 2048, nullptr, 0, nullptr, 0, 0, 16384, 1024, 1024, det);

    // ---- attention: ir-side first (frees q_v), then vis-side
    attn_kernel<<<2048, 256, 0, stream>>>(q_v, k_i, vt_i, att_i);   // att_ir  (overlays lnbuf)
    attn_kernel<<<2048, 256, 0, stream>>>(q_i, k_v, vt_v, att_v);   // att_vis (overlays q_v)

    // ---- output projection + residual blend -> d_out
    gemm256<2><<<256, 512, 0, stream>>>(att_v, wto_v, d_out, 0,        bo_v, 0, rgb, 0, coeffs, 0, 1, 16384, 1024, 1024, det);
    gemm256<2><<<256, 512, 0, stream>>>(att_i, wto_i, d_out, 16777216, bo_i, 0, ir,  0, coeffs, 2, 3, 16384, 1024, 1024, det);

    // ---- MLP vis: LN -> W1+gelu -> W2 + blend (in-place on d_out[0])
    ln_kernel<<<16384, 128, 0, stream>>>(d_out, 0, bln_g, bln_b, mlp_ln, det);
    gemm256<1><<<1024, 512, 0, stream>>>(mlp_ln, wt1_v, Hbuf, 0, b1_v, 0, nullptr, 0, nullptr, 0, 0, 16384, 4096, 1024, det);
    gemm256<2><<<256,  512, 0, stream>>>(Hbuf, wt2_v, d_out, 0, b2_v, 0, d_out, 0, coeffs, 4, 5, 16384, 1024, 4096, det);

    // ---- MLP ir
    ln_kernel<<<16384, 128, 0, stream>>>(d_out, 16777216, bln_g, bln_b, mlp_ln, det);
    gemm256<1><<<1024, 512, 0, stream>>>(mlp_ln, wt1_i, Hbuf, 0, b1_i, 0, nullptr, 0, nullptr, 0, 0, 16384, 4096, 1024, det);
    gemm256<2><<<256,  512, 0, stream>>>(Hbuf, wt2_i, d_out, 16777216, b2_i, 0, d_out, 16777216, coeffs, 6, 7, 16384, 1024, 4096, det);
}

// Round 2
// 1747.792 us; speedup vs baseline: 1.4173x; 1.2033x over previous
//
#include <hip/hip_runtime.h>
#include <math.h>

using bf16   = __bf16;
using bf16x8 = __attribute__((ext_vector_type(8))) __bf16;
using f32x4  = __attribute__((ext_vector_type(4))) float;

typedef __attribute__((address_space(1))) const void* gc_ptr;
typedef __attribute__((address_space(3))) void*       ls_ptr;

#define MFMA16(a, b, c) __builtin_amdgcn_mfma_f32_16x16x32_bf16((a), (b), (c), 0, 0, 0)

// Runtime dtype detection: ln1_g[0] == 1.0f. fp32 -> 0x3F800000, bf16 pair -> 0x3F803F80.
__device__ __forceinline__ bool det_f32(const unsigned* det) { return *det == 0x3F800000u; }
__device__ __forceinline__ float ldx(const void* p, size_t i, bool f) {
    return f ? ((const float*)p)[i] : (float)(((const bf16*)p)[i]);
}

// ---------------------------------------------------------------------------
// Weight transpose: in (R x C, external dtype) -> out (C x R, bf16)
// ---------------------------------------------------------------------------
__global__ __launch_bounds__(256) void transpose2d(const void* __restrict__ in, size_t ioff,
                                                   bf16* __restrict__ out,
                                                   int R, int C, const unsigned* det)
{
    const bool f = det_f32(det);
    __shared__ bf16 t[32][33];
    int c0 = blockIdx.x * 32, r0 = blockIdx.y * 32;
    int tx = threadIdx.x, ty = threadIdx.y;
    #pragma unroll
    for (int i = ty; i < 32; i += 8)
        t[i][tx] = (bf16)ldx(in, ioff + (size_t)(r0 + i) * C + c0 + tx, f);
    __syncthreads();
    #pragma unroll
    for (int i = ty; i < 32; i += 8)
        out[(size_t)(c0 + i) * R + r0 + tx] = t[tx][i];
}

// ---------------------------------------------------------------------------
// LayerNorm over D=1024 (external-dtype x/g/b -> bf16 y). grid=rows, block=128.
// ---------------------------------------------------------------------------
__global__ __launch_bounds__(128) void ln_kernel(const void* __restrict__ x, size_t xoff,
                                                 const void* __restrict__ g,
                                                 const void* __restrict__ b,
                                                 bf16* __restrict__ y, const unsigned* det)
{
    const bool f = det_f32(det);
    int row = blockIdx.x, tid = threadIdx.x;
    float fv[8], s = 0.f, sq = 0.f;
    if (f) {
        const float* xp = (const float*)x + xoff + (size_t)row * 1024 + tid * 8;
        float4 a = *(const float4*)xp;
        float4 c = *(const float4*)(xp + 4);
        fv[0] = a.x; fv[1] = a.y; fv[2] = a.z; fv[3] = a.w;
        fv[4] = c.x; fv[5] = c.y; fv[6] = c.z; fv[7] = c.w;
    } else {
        bf16x8 xv = *(const bf16x8*)((const bf16*)x + xoff + (size_t)row * 1024 + tid * 8);
        #pragma unroll
        for (int j = 0; j < 8; ++j) fv[j] = (float)xv[j];
    }
    #pragma unroll
    for (int j = 0; j < 8; ++j) { s += fv[j]; sq += fv[j] * fv[j]; }
    #pragma unroll
    for (int d = 1; d < 64; d <<= 1) { s += __shfl_xor(s, d, 64); sq += __shfl_xor(sq, d, 64); }
    __shared__ float ss[2], sq2[2];
    int w = tid >> 6;
    if ((tid & 63) == 0) { ss[w] = s; sq2[w] = sq; }
    __syncthreads();
    s = ss[0] + ss[1]; sq = sq2[0] + sq2[1];
    float mean = s * (1.f / 1024.f);
    float var  = sq * (1.f / 1024.f) - mean * mean;
    float rstd = rsqrtf(var + 1e-5f);
    bf16x8 o;
    #pragma unroll
    for (int j = 0; j < 8; ++j)
        o[j] = (bf16)((fv[j] - mean) * rstd * ldx(g, tid * 8 + j, f) + ldx(b, tid * 8 + j, f));
    *(bf16x8*)(y + (size_t)row * 1024 + tid * 8) = o;
}

// ---------------------------------------------------------------------------
// OLD 128x128 GEMM, kept ONLY for EPI 3 (per-head transposed V write).
// ---------------------------------------------------------------------------
template <int EPI>
__global__ __launch_bounds__(256) void gemm_bt(const bf16* __restrict__ A,
                                               const bf16* __restrict__ BT,
                                               void* __restrict__ Cp, size_t coff,
                                               const void* __restrict__ bias, size_t boff,
                                               const void* __restrict__ resid, size_t roff,
                                               const void* __restrict__ coeffs, int ciR, int ciV,
                                               int M, int N, int K, const unsigned* det)
{
    const bool f = det_f32(det);
    __shared__ alignas(16) bf16 smem[17408];   // As(8192) + Bs(8192); EPI3 reuses as 128x136
    bf16* As = smem;
    bf16* Bs = smem + 8192;
    const int tid  = threadIdx.x;
    const int lane = tid & 63;
    const int w    = tid >> 6;
    const int wm   = w >> 1, wn = w & 1;
    const int quad = lane >> 4, l16 = lane & 15;
    const int bm = blockIdx.x * 128, bn = blockIdx.y * 128;

    f32x4 acc[4][4] = {};

    for (int k0 = 0; k0 < K; k0 += 64) {
        #pragma unroll
        for (int i = 0; i < 4; ++i) {
            int u = i * 256 + tid;
            int r = u >> 3, c = (u & 7) * 8;
            __builtin_amdgcn_global_load_lds((gc_ptr)(A + (size_t)(bm + r) * K + k0 + c),
                                             (ls_ptr)(As + (size_t)(i * 256 + (tid & 192)) * 8),
                                             16, 0, 0);
        }
        #pragma unroll
        for (int i = 0; i < 4; ++i) {
            int u = i * 256 + tid;
            int r = u >> 3, c = (u & 7) * 8;
            __builtin_amdgcn_global_load_lds((gc_ptr)(BT + (size_t)(bn + r) * K + k0 + c),
                                             (ls_ptr)(Bs + (size_t)(i * 256 + (tid & 192)) * 8),
                                             16, 0, 0);
        }
        __syncthreads();
        #pragma unroll
        for (int kk = 0; kk < 2; ++kk) {
            bf16x8 af[4], bfr[4];
            #pragma unroll
            for (int i = 0; i < 4; ++i)
                af[i] = *(const bf16x8*)(As + (wm * 64 + i * 16 + l16) * 64 + kk * 32 + quad * 8);
            #pragma unroll
            for (int i = 0; i < 4; ++i)
                bfr[i] = *(const bf16x8*)(Bs + (wn * 64 + i * 16 + l16) * 64 + kk * 32 + quad * 8);
            #pragma unroll
            for (int im = 0; im < 4; ++im)
                #pragma unroll
                for (int in = 0; in < 4; ++in)
                    acc[im][in] = MFMA16(af[im], bfr[in], acc[im][in]);
        }
        __syncthreads();
    }

    if (EPI == 3) {
        // transpose through LDS: T[dk][n], stride 136 (16B-aligned rows)
        bf16* T = smem;
        #pragma unroll
        for (int in = 0; in < 4; ++in) {
            int dk = wn * 64 + in * 16 + l16;
            float bv = ldx(bias, boff + bn + dk, f);
            #pragma unroll
            for (int im = 0; im < 4; ++im)
                #pragma unroll
                for (int r = 0; r < 4; ++r) {
                    int n = wm * 64 + im * 16 + quad * 4 + r;
                    T[dk * 136 + n] = (bf16)(acc[im][in][r] + bv);
                }
        }
        __syncthreads();
        int bq = bm >> 8, n0 = bm & 255, h = bn >> 7;
        bf16* dst = (bf16*)Cp + ((size_t)(bq * 8 + h) * 128) * 256 + n0;
        #pragma unroll
        for (int it = 0; it < 8; ++it) {
            int idx = it * 256 + tid;
            int dk = idx >> 4, ch = idx & 15;
            *(bf16x8*)(dst + (size_t)dk * 256 + ch * 8) = *(const bf16x8*)(T + dk * 136 + ch * 8);
        }
        return;
    }

    float cR = 0.f, cV = 0.f;
    if (EPI == 2) { cR = ldx(coeffs, ciR, f); cV = ldx(coeffs, ciV, f); }
    #pragma unroll
    for (int in = 0; in < 4; ++in) {
        int col = bn + wn * 64 + in * 16 + l16;
        float bv = ldx(bias, boff + col, f);
        #pragma unroll
        for (int im = 0; im < 4; ++im) {
            #pragma unroll
            for (int r = 0; r < 4; ++r) {
                int row = bm + wm * 64 + im * 16 + quad * 4 + r;
                float v = acc[im][in][r] + bv;
                if (EPI == 1) v = 0.5f * v * (1.f + erff(v * 0.7071067811865476f));
                size_t o = coff + (size_t)row * N + col;
                if (EPI == 2) {
                    v = cR * ldx(resid, roff + (size_t)row * N + col, f) + cV * v;
                    if (f) ((float*)Cp)[o] = v; else ((bf16*)Cp)[o] = (bf16)v;
                } else {
                    ((bf16*)Cp)[o] = (bf16)v;
                }
            }
        }
    }
}

// ---------------------------------------------------------------------------
// 256x256-tile 8-phase GEMM (T2 swizzle + T3/T4 counted vmcnt + T5 setprio).
// 512 threads = 8 waves (2M x 4N), each wave owns a 128x64 output tile.
// BK=64; LDS = 2 buffers x (A 256x64 + B 256x64) bf16 = 128 KiB; 1 block/CU.
// See R0/R1 notes: counted vmcnt(6), never 0 in steady state.
// R1 changes: (a) per-XCD contiguous-bx block mapping (A-dup 1x across XCDs),
//             (b) LDS-staged vectorized epilogue (full-line writes, vector resid).
// ---------------------------------------------------------------------------
template <int BS>
__device__ __forceinline__ void stage_h(const bf16* __restrict__ src, int Kd, bf16* dst,
                                        int h, int tid, size_t base)
{
    const int msk = (1 << BS) - 1;
    #pragma unroll
    for (int j = 0; j < 2; ++j) {
        int rl  = j * 64 + (tid >> 3);                                   // logical row 0..127
        int rp  = (rl & msk) + ((rl >> BS) << (BS + 1)) + (h << BS);     // physical row 0..255
        int rl0 = j * 64 + ((tid & 448) >> 3);                           // wave-uniform first row
        int rp0 = (rl0 & msk) + ((rl0 >> BS) << (BS + 1)) + (h << BS);
        int cs  = ((tid & 7) ^ ((tid >> 3) & 7)) << 3;                   // pre-swizzled source col
        __builtin_amdgcn_global_load_lds((gc_ptr)(src + base + (size_t)rp * Kd + cs),
                                         (ls_ptr)(dst + rp0 * 64), 16, 0, 0);
    }
}

#define BARR()  asm volatile("s_barrier" ::: "memory")
#define LGKM0() asm volatile("s_waitcnt lgkmcnt(0)" ::: "memory")

#define LD_AF(AB, MH)                                                                   \
    _Pragma("unroll") for (int m_ = 0; m_ < 4; ++m_)                                    \
    _Pragma("unroll") for (int kk_ = 0; kk_ < 2; ++kk_)                                 \
        af[m_][kk_] = *(const bf16x8*)((AB) + (wm * 128 + (MH) * 64 + m_ * 16 + l16) * 64 \
                                       + ((kk_ * 32 + quad * 8) ^ swzc));

#define LD_BF(BB, NH)                                                                   \
    _Pragma("unroll") for (int n_ = 0; n_ < 2; ++n_)                                    \
    _Pragma("unroll") for (int kk_ = 0; kk_ < 2; ++kk_)                                 \
        bff[(NH) * 2 + n_][kk_] = *(const bf16x8*)((BB) + (wn * 64 + (NH) * 32 + n_ * 16 + l16) * 64 \
                                                   + ((kk_ * 32 + quad * 8) ^ swzc));

#define MMQ(MH, NH)                                                                     \
    _Pragma("unroll") for (int m_ = 0; m_ < 4; ++m_)                                    \
    _Pragma("unroll") for (int n_ = 0; n_ < 2; ++n_)                                    \
    _Pragma("unroll") for (int kk_ = 0; kk_ < 2; ++kk_)                                 \
        acc[(MH) * 4 + m_][(NH) * 2 + n_] =                                             \
            MFMA16(af[m_][kk_], bff[(NH) * 2 + n_][kk_], acc[(MH) * 4 + m_][(NH) * 2 + n_]);

#define KTILE(P, T)                                                                     \
    {                                                                                   \
        const bf16* Ab = smem + (P) * 32768;                                            \
        const bf16* Bb = smem + (P) * 32768 + 16384;                                    \
        bf16* An = smem + (1 - (P)) * 32768;                                            \
        bf16* Ac = smem + (P) * 32768;                                                  \
        bf16* Bc = smem + (P) * 32768 + 16384;                                          \
        /* P1: af(mh=0)+bf(nh=0); stage A-hi(t+1) */                                    \
        LD_AF(Ab, 0)                                                                    \
        LD_BF(Bb, 0)                                                                    \
        if ((T) + 1 < NT) stage_h<6>(A, K, An, 1, tid, Arow + (size_t)((T) + 1) * 64);  \
        BARR(); LGKM0();                                                                \
        __builtin_amdgcn_s_setprio(1); MMQ(0, 0) __builtin_amdgcn_s_setprio(0);         \
        BARR();                                                                         \
        /* P2: bf(nh=1); stage A-lo(t+2) */                                             \
        LD_BF(Bb, 1)                                                                    \
        if ((T) + 2 < NT) stage_h<6>(A, K, Ac, 0, tid, Arow + (size_t)((T) + 2) * 64);  \
        BARR(); LGKM0();                                                                \
        __builtin_amdgcn_s_setprio(1); MMQ(0, 1) __builtin_amdgcn_s_setprio(0);         \
        BARR();                                                                         \
        /* P3: af(mh=1); stage B-lo(t+2) */                                             \
        LD_AF(Ab, 1)                                                                    \
        if ((T) + 2 < NT) stage_h<5>(BT, K, Bc, 0, tid, Brow + (size_t)((T) + 2) * 64); \
        BARR(); LGKM0();                                                                \
        __builtin_amdgcn_s_setprio(1); MMQ(1, 0) __builtin_amdgcn_s_setprio(0);         \
        BARR();                                                                         \
        /* P4: stage B-hi(t+2); counted vmcnt at K-tile boundary */                     \
        if ((T) + 2 < NT) stage_h<5>(BT, K, Bc, 1, tid, Brow + (size_t)((T) + 2) * 64); \
        BARR();                                                                         \
        __builtin_amdgcn_s_setprio(1); MMQ(1, 1) __builtin_amdgcn_s_setprio(0);         \
        if ((T) + 1 < NT) {                                                             \
            if ((T) + 2 < NT) { asm volatile("s_waitcnt vmcnt(6)" ::: "memory"); }      \
            else              { asm volatile("s_waitcnt vmcnt(0)" ::: "memory"); }      \
            BARR();                                                                     \
        }                                                                               \
    }

template <int EPI>
__global__ __launch_bounds__(512, 2) void gemm256(const bf16* __restrict__ A,
                                                  const bf16* __restrict__ BT,
                                                  void* __restrict__ Cp, size_t coff,
                                                  const void* __restrict__ bias, size_t boff,
                                                  const void* __restrict__ resid, size_t roff,
                                                  const void* __restrict__ coeffs, int ciR, int ciV,
                                                  int M, int N, int K, const unsigned* det)
{
    const bool f = det_f32(det);
    __shared__ alignas(16) bf16 smem[65536];   // 128 KiB: 2 x (A 16384 + B 16384) elems

    // Per-XCD contiguous-bx chunk mapping (requires nbx = M/256 = 64, i.e. M=16384):
    // xcd = bid&7 owns bx in [xcd*8, xcd*8+8) for ALL by -> A fetched once chip-wide;
    // concurrent blocks on an XCD are K-synchronized so per-K-step footprint is tiny.
    const int bid = blockIdx.x;
    const int xcd = bid & 7, ch = bid >> 3;
    const int bx = xcd * 8 + (ch & 7);
    const int by = ch >> 3;
    const int bm = bx << 8, bn = by << 8;

    const int tid  = threadIdx.x;
    const int lane = tid & 63, w = tid >> 6;
    const int wm = w >> 2, wn = w & 3;
    const int quad = lane >> 4, l16 = lane & 15;
    const int swzc = (l16 & 7) << 3;

    const int NT = K >> 6;
    const size_t Arow = (size_t)bm * K;
    const size_t Brow = (size_t)bn * K;

    f32x4 acc[8][4] = {};
    bf16x8 af[4][2], bff[4][2];

    // prologue: tile0 (all 4 halves) + tile1 (A-lo, B-lo, B-hi) -> 14 loads, keep 6 in flight
    stage_h<6>(A,  K, smem,         0, tid, Arow);
    stage_h<6>(A,  K, smem,         1, tid, Arow);
    stage_h<5>(BT, K, smem + 16384, 0, tid, Brow);
    stage_h<5>(BT, K, smem + 16384, 1, tid, Brow);
    stage_h<6>(A,  K, smem + 32768, 0, tid, Arow + 64);
    stage_h<5>(BT, K, smem + 49152, 0, tid, Brow + 64);
    stage_h<5>(BT, K, smem + 49152, 1, tid, Brow + 64);
    asm volatile("s_waitcnt vmcnt(6)" ::: "memory");
    BARR();

    for (int t = 0; t < NT; t += 2) {   // NT is even for all our shapes (16 or 64)
        KTILE(0, t)
        KTILE(1, t + 1)
    }

    // ---- LDS-staged vectorized epilogue ----
    // All global_load_lds drained (vmcnt(0) at last tile boundary); sync, then reuse smem.
    __syncthreads();
    float cR = 0.f, cV = 0.f;
    if (EPI == 2) { cR = ldx(coeffs, ciR, f); cV = ldx(coeffs, ciV, f); }

    if (EPI == 2 && f) {
        // fp32 out with fp32 resid: 4 passes of 64 rows, stride 264 f32 (bank-clean).
        float* T = (float*)smem;
        for (int p = 0; p < 4; ++p) {
            if (wm == (p >> 1)) {
                const int mh = p & 1;
                #pragma unroll
                for (int n = 0; n < 4; ++n) {
                    float bv = ldx(bias, boff + bn + wn * 64 + n * 16 + l16, f);
                    #pragma unroll
                    for (int m2 = 0; m2 < 4; ++m2) {
                        #pragma unroll
                        for (int r = 0; r < 4; ++r)
                            T[(m2 * 16 + quad * 4 + r) * 264 + wn * 64 + n * 16 + l16] =
                                acc[mh * 4 + m2][n][r] + bv;
                    }
                }
            }
            __syncthreads();
            #pragma unroll
            for (int i = 0; i < 8; ++i) {
                int u = i * 512 + tid;                 // 0..4095
                int lr = u >> 6, c = (u & 63) * 4;     // 64 rows x 64 float4 chunks
                int row = bm + p * 64 + lr;
                size_t o = coff + (size_t)row * N + bn + c;
                float4 rv = *(const float4*)((const float*)resid + roff + (size_t)row * N + bn + c);
                float4 tv = *(const float4*)(T + lr * 264 + c);
                float4 ov;
                ov.x = cR * rv.x + cV * tv.x;
                ov.y = cR * rv.y + cV * tv.y;
                ov.z = cR * rv.z + cV * tv.z;
                ov.w = cR * rv.w + cV * tv.w;
                *(float4*)((float*)Cp + o) = ov;
            }
            __syncthreads();
        }
    } else {
        // bf16 out (EPI 0/1, or EPI2 with bf16 resid): 2 passes of 128 rows, stride 272 bf16.
        bf16* T = smem;
        for (int p = 0; p < 2; ++p) {
            if (wm == p) {
                #pragma unroll
                for (int n = 0; n < 4; ++n) {
                    float bv = ldx(bias, boff + bn + wn * 64 + n * 16 + l16, f);
                    #pragma unroll
                    for (int m = 0; m < 8; ++m) {
                        #pragma unroll
                        for (int r = 0; r < 4; ++r) {
                            float v = acc[m][n][r] + bv;
                            if (EPI == 1) v = 0.5f * v * (1.f + erff(v * 0.7071067811865476f));
                            T[(m * 16 + quad * 4 + r) * 272 + wn * 64 + n * 16 + l16] = (bf16)v;
                        }
                    }
                }
            }
            __syncthreads();
            #pragma unroll
            for (int i = 0; i < 8; ++i) {
                int u = i * 512 + tid;                 // 0..4095
                int lr = u >> 5, c = (u & 31) * 8;     // 128 rows x 32 bf16x8 chunks
                int row = bm + p * 128 + lr;
                bf16x8 tv = *(const bf16x8*)(T + lr * 272 + c);
                if (EPI == 2) {
                    bf16x8 rv = *(const bf16x8*)((const bf16*)resid + roff + (size_t)row * N + bn + c);
                    #pragma unroll
                    for (int j = 0; j < 8; ++j)
                        tv[j] = (bf16)(cR * (float)rv[j] + cV * (float)tv[j]);
                }
                *(bf16x8*)((bf16*)Cp + coff + (size_t)row * N + bn + c) = tv;
            }
            __syncthreads();
        }
    }
}

// ---------------------------------------------------------------------------
// Cross-attention, one stream: grid 2048 = 64 b x 8 h x 4 row-blocks of 64.
// ---------------------------------------------------------------------------
__global__ __launch_bounds__(256) void attn_kernel(const bf16* __restrict__ Q,
                                                   const bf16* __restrict__ K,
                                                   const bf16* __restrict__ VT,
                                                   bf16* __restrict__ O)
{
    const int bi = blockIdx.x;
    const int mb = bi & 3, h = (bi >> 2) & 7, b = bi >> 5;
    const bf16* Qp = Q + (size_t)b * (256 * 1024) + h * 128;
    const bf16* Kp = K + (size_t)b * (256 * 1024) + h * 128;
    const bf16* Vp = VT + (size_t)(b * 8 + h) * (128 * 256);
    bf16* Op = O + (size_t)b * (256 * 1024) + h * 128;
    const int m0 = mb * 64;

    const int tid = threadIdx.x, lane = tid & 63, w = tid >> 6;
    const int quad = lane >> 4, l16 = lane & 15;

    f32x4 sa[4][4] = {};
    #pragma unroll
    for (int k0 = 0; k0 < 128; k0 += 32) {
        bf16x8 aq[4], bk[4];
        #pragma unroll
        for (int i = 0; i < 4; ++i)
            aq[i] = *(const bf16x8*)(Qp + (size_t)(m0 + i * 16 + l16) * 1024 + k0 + quad * 8);
        #pragma unroll
        for (int i = 0; i < 4; ++i)
            bk[i] = *(const bf16x8*)(Kp + (size_t)(w * 64 + i * 16 + l16) * 1024 + k0 + quad * 8);
        #pragma unroll
        for (int im = 0; im < 4; ++im)
            #pragma unroll
            for (int in = 0; in < 4; ++in)
                sa[im][in] = MFMA16(aq[im], bk[in], sa[im][in]);
    }
    const float scale = 0.088388347648318447f;  // 1/sqrt(128)
    #pragma unroll
    for (int im = 0; im < 4; ++im)
        #pragma unroll
        for (int in = 0; in < 4; ++in)
            #pragma unroll
            for (int r = 0; r < 4; ++r)
                sa[im][in][r] *= scale;

    __shared__ float red1[4][64];
    __shared__ float red2[4][64];
    __shared__ alignas(16) bf16 Ps[64 * 264];

    float rmax[4][4];
    #pragma unroll
    for (int im = 0; im < 4; ++im)
        #pragma unroll
        for (int r = 0; r < 4; ++r) {
            float m = fmaxf(fmaxf(sa[im][0][r], sa[im][1][r]), fmaxf(sa[im][2][r], sa[im][3][r]));
            #pragma unroll
            for (int d = 1; d < 16; d <<= 1) m = fmaxf(m, __shfl_xor(m, d, 64));
            rmax[im][r] = m;
        }
    if (l16 == 0)
        #pragma unroll
        for (int im = 0; im < 4; ++im)
            #pragma unroll
            for (int r = 0; r < 4; ++r)
                red1[w][im * 16 + quad * 4 + r] = rmax[im][r];
    __syncthreads();
    #pragma unroll
    for (int im = 0; im < 4; ++im)
        #pragma unroll
        for (int r = 0; r < 4; ++r) {
            int row = im * 16 + quad * 4 + r;
            rmax[im][r] = fmaxf(fmaxf(red1[0][row], red1[1][row]),
                                fmaxf(red1[2][row], red1[3][row]));
        }

    float rsum[4][4];
    #pragma unroll
    for (int im = 0; im < 4; ++im)
        #pragma unroll
        for (int r = 0; r < 4; ++r) {
            float t = 0.f;
            #pragma unroll
            for (int in = 0; in < 4; ++in) {
                float e = __expf(sa[im][in][r] - rmax[im][r]);
                sa[im][in][r] = e;
                t += e;
            }
            #pragma unroll
            for (int d = 1; d < 16; d <<= 1) t += __shfl_xor(t, d, 64);
            rsum[im][r] = t;
        }
    if (l16 == 0)
        #pragma unroll
        for (int im = 0; im < 4; ++im)
            #pragma unroll
            for (int r = 0; r < 4; ++r)
                red2[w][im * 16 + quad * 4 + r] = rsum[im][r];
    __syncthreads();
    #pragma unroll
    for (int im = 0; im < 4; ++im)
        #pragma unroll
        for (int r = 0; r < 4; ++r) {
            int row = im * 16 + quad * 4 + r;
            float inv = 1.f / (red2[0][row] + red2[1][row] + red2[2][row] + red2[3][row]);
            #pragma unroll
            for (int in = 0; in < 4; ++in)
                Ps[row * 264 + w * 64 + in * 16 + l16] = (bf16)(sa[im][in][r] * inv);
        }
    __syncthreads();

    f32x4 oa[4][2] = {};
    #pragma unroll
    for (int k0 = 0; k0 < 256; k0 += 32) {
        bf16x8 ap[4], bv[2];
        #pragma unroll
        for (int im = 0; im < 4; ++im)
            ap[im] = *(const bf16x8*)(Ps + (im * 16 + l16) * 264 + k0 + quad * 8);
        #pragma unroll
        for (int in = 0; in < 2; ++in)
            bv[in] = *(const bf16x8*)(Vp + (size_t)(w * 32 + in * 16 + l16) * 256 + k0 + quad * 8);
        #pragma unroll
        for (int im = 0; im < 4; ++im)
            #pragma unroll
            for (int in = 0; in < 2; ++in)
                oa[im][in] = MFMA16(ap[im], bv[in], oa[im][in]);
    }
    #pragma unroll
    for (int im = 0; im < 4; ++im)
        #pragma unroll
        for (int in = 0; in < 2; ++in)
            #pragma unroll
            for (int r = 0; r < 4; ++r) {
                int row = m0 + im * 16 + quad * 4 + r;
                int col = w * 32 + in * 16 + l16;
                Op[(size_t)row * 1024 + col] = (bf16)oa[im][in][r];
            }
}

// ---------------------------------------------------------------------------
extern "C" void kernel_launch(void* const* d_in, const int* in_sizes, int n_in,
                              void* d_out, int out_size, void* d_ws, size_t ws_size,
                              hipStream_t stream)
{
    const void* rgb    = d_in[0];
    const void* ir     = d_in[1];
    const void* ln1_g  = d_in[2];
    const void* ln1_b  = d_in[3];
    const void* ln2_g  = d_in[4];
    const void* ln2_b  = d_in[5];
    const void* Wqkv_v = d_in[6];
    const void* bqkv_v = d_in[7];
    const void* Wqkv_i = d_in[8];
    const void* bqkv_i = d_in[9];
    const void* Wo_v   = d_in[10];
    const void* bo_v   = d_in[11];
    const void* Wo_i   = d_in[12];
    const void* bo_i   = d_in[13];
    const void* bln_g  = d_in[14];
    const void* bln_b  = d_in[15];
    const void* W1_v   = d_in[16];
    const void* b1_v   = d_in[17];
    const void* W2_v   = d_in[18];
    const void* b2_v   = d_in[19];
    const void* W1_i   = d_in[20];
    const void* b1_i   = d_in[21];
    const void* W2_i   = d_in[22];
    const void* b2_i   = d_in[23];
    const void* coeffs = d_in[24];
    const unsigned* det = (const unsigned*)ln1_g;

    // workspace layout (bytes), peak 272,629,760 (~260 MiB)
    char* ws = (char*)d_ws;
    bf16* wtq_v  = (bf16*)(ws + 0);            // 6 MiB (3x 1024x1024)
    bf16* wtq_i  = (bf16*)(ws + 6291456);
    bf16* wto_v  = (bf16*)(ws + 12582912);     // 2 MiB
    bf16* wto_i  = (bf16*)(ws + 14680064);
    bf16* wt1_v  = (bf16*)(ws + 16777216);     // 8 MiB (4096x1024)
    bf16* wt1_i  = (bf16*)(ws + 25165824);
    bf16* wt2_v  = (bf16*)(ws + 33554432);     // 8 MiB (1024x4096)
    bf16* wt2_i  = (bf16*)(ws + 41943040);
    bf16* lnbuf  = (bf16*)(ws + 50331648);     // 32 MiB; reused as att_i
    bf16* q_v    = (bf16*)(ws + 83886080);     // 32 MiB; reused as att_v, then Hbuf
    bf16* k_v    = (bf16*)(ws + 117440512);
    bf16* vt_v   = (bf16*)(ws + 150994944);
    bf16* q_i    = (bf16*)(ws + 184549376);
    bf16* k_i    = (bf16*)(ws + 218103808);    // reused as mlp_ln
    bf16* vt_i   = (bf16*)(ws + 251658240);    // ends 285212672
    bf16* att_i  = lnbuf;
    bf16* att_v  = q_v;
    bf16* Hbuf   = (bf16*)(ws + 83886080);     // 128 MiB (16384x4096)
    bf16* mlp_ln = (bf16*)(ws + 218103808);

    dim3 tb(32, 8);
    // ---- weight transposes (external dtype -> bf16 N x K)
    for (int t = 0; t < 3; ++t) {
        transpose2d<<<dim3(32, 32), tb, 0, stream>>>(Wqkv_v, (size_t)t * 1048576, wtq_v + (size_t)t * 1048576, 1024, 1024, det);
        transpose2d<<<dim3(32, 32), tb, 0, stream>>>(Wqkv_i, (size_t)t * 1048576, wtq_i + (size_t)t * 1048576, 1024, 1024, det);
    }
    transpose2d<<<dim3(32, 32),  tb, 0, stream>>>(Wo_v, 0, wto_v, 1024, 1024, det);
    transpose2d<<<dim3(32, 32),  tb, 0, stream>>>(Wo_i, 0, wto_i, 1024, 1024, det);
    transpose2d<<<dim3(128, 32), tb, 0, stream>>>(W1_v, 0, wt1_v, 1024, 4096, det);
    transpose2d<<<dim3(128, 32), tb, 0, stream>>>(W1_i, 0, wt1_i, 1024, 4096, det);
    transpose2d<<<dim3(32, 128), tb, 0, stream>>>(W2_v, 0, wt2_v, 4096, 1024, det);
    transpose2d<<<dim3(32, 128), tb, 0, stream>>>(W2_i, 0, wt2_i, 4096, 1024, det);

    // ---- LN + QKV (Q,K via 256^2 8-phase; V via old EPI3 per-head transpose)
    ln_kernel<<<16384, 128, 0, stream>>>(rgb, 0, ln1_g, ln1_b, lnbuf, det);
    gemm256<0><<<256, 512, 0, stream>>>(lnbuf, wtq_v + 0 * 1048576, q_v, 0, bqkv_v, 0,    nullptr, 0, nullptr, 0, 0, 16384, 1024, 1024, det);
    gemm256<0><<<256, 512, 0, stream>>>(lnbuf, wtq_v + 1 * 1048576, k_v, 0, bqkv_v, 1024, nullptr, 0, nullptr, 0, 0, 16384, 1024, 1024, det);
    gemm_bt<3><<<dim3(128, 8), 256, 0, stream>>>(lnbuf, wtq_v + 2 * 1048576, vt_v, 0, bqkv_v, 2048, nullptr, 0, nullptr, 0, 0, 16384, 1024, 1024, det);
    ln_kernel<<<16384, 128, 0, stream>>>(ir, 0, ln2_g, ln2_b, lnbuf, det);
    gemm256<0><<<256, 512, 0, stream>>>(lnbuf, wtq_i + 0 * 1048576, q_i, 0, bqkv_i, 0,    nullptr, 0, nullptr, 0, 0, 16384, 1024, 1024, det);
    gemm256<0><<<256, 512, 0, stream>>>(lnbuf, wtq_i + 1 * 1048576, k_i, 0, bqkv_i, 1024, nullptr, 0, nullptr, 0, 0, 16384, 1024, 1024, det);
    gemm_bt<3><<<dim3(128, 8), 256, 0, stream>>>(lnbuf, wtq_i + 2 * 1048576, vt_i, 0, bqkv_i, 2048, nullptr, 0, nullptr, 0, 0, 16384, 1024, 1024, det);

    // ---- attention: ir-side first (frees q_v), then vis-side
    attn_kernel<<<2048, 256, 0, stream>>>(q_v, k_i, vt_i, att_i);   // att_ir  (overlays lnbuf)
    attn_kernel<<<2048, 256, 0, stream>>>(q_i, k_v, vt_v, att_v);   // att_vis (overlays q_v)

    // ---- output projection + residual blend -> d_out
    gemm256<2><<<256, 512, 0, stream>>>(att_v, wto_v, d_out, 0,        bo_v, 0, rgb, 0, coeffs, 0, 1, 16384, 1024, 1024, det);
    gemm256<2><<<256, 512, 0, stream>>>(att_i, wto_i, d_out, 16777216, bo_i, 0, ir,  0, coeffs, 2, 3, 16384, 1024, 1024, det);

    // ---- MLP vis: LN -> W1+gelu -> W2 + blend (in-place on d_out[0])
    ln_kernel<<<16384, 128, 0, stream>>>(d_out, 0, bln_g, bln_b, mlp_ln, det);
    gemm256<1><<<1024, 512, 0, stream>>>(mlp_ln, wt1_v, Hbuf, 0, b1_v, 0, nullptr, 0, nullptr, 0, 0, 16384, 4096, 1024, det);
    gemm256<2><<<256,  512, 0, stream>>>(Hbuf, wt2_v, d_out, 0, b2_v, 0, d_out, 0, coeffs, 4, 5, 16384, 1024, 4096, det);

    // ---- MLP ir
    ln_kernel<<<16384, 128, 0, stream>>>(d_out, 16777216, bln_g, bln_b, mlp_ln, det);
    gemm256<1><<<1024, 512, 0, stream>>>(mlp_ln, wt1_i, Hbuf, 0, b1_i, 0, nullptr, 0, nullptr, 0, 0, 16384, 4096, 1024, det);
    gemm256<2><<<256,  512, 0, stream>>>(Hbuf, wt2_i, d_out, 16777216, b2_i, 0, d_out, 16777216, coeffs, 6, 7, 16384, 1024, 4096, det);
}

// Round 3
// 1708.913 us; speedup vs baseline: 1.4495x; 1.0228x over previous
//
#include <hip/hip_runtime.h>
#include <math.h>

using bf16   = __bf16;
using bf16x8 = __attribute__((ext_vector_type(8))) __bf16;
using f32x4  = __attribute__((ext_vector_type(4))) float;

typedef __attribute__((address_space(1))) const void* gc_ptr;
typedef __attribute__((address_space(3))) void*       ls_ptr;

#define MFMA16(a, b, c) __builtin_amdgcn_mfma_f32_16x16x32_bf16((a), (b), (c), 0, 0, 0)

// Runtime dtype detection: ln1_g[0] == 1.0f. fp32 -> 0x3F800000, bf16 pair -> 0x3F803F80.
__device__ __forceinline__ bool det_f32(const unsigned* det) { return *det == 0x3F800000u; }
__device__ __forceinline__ float ldx(const void* p, size_t i, bool f) {
    return f ? ((const float*)p)[i] : (float)(((const bf16*)p)[i]);
}

// ---------------------------------------------------------------------------
// Weight transpose: in (R x C, external dtype) -> out (C x R, bf16)
// ---------------------------------------------------------------------------
__global__ __launch_bounds__(256) void transpose2d(const void* __restrict__ in, size_t ioff,
                                                   bf16* __restrict__ out,
                                                   int R, int C, const unsigned* det)
{
    const bool f = det_f32(det);
    __shared__ bf16 t[32][33];
    int c0 = blockIdx.x * 32, r0 = blockIdx.y * 32;
    int tx = threadIdx.x, ty = threadIdx.y;
    #pragma unroll
    for (int i = ty; i < 32; i += 8)
        t[i][tx] = (bf16)ldx(in, ioff + (size_t)(r0 + i) * C + c0 + tx, f);
    __syncthreads();
    #pragma unroll
    for (int i = ty; i < 32; i += 8)
        out[(size_t)(c0 + i) * R + r0 + tx] = t[tx][i];
}

// ---------------------------------------------------------------------------
// LayerNorm over D=1024 (external-dtype x/g/b -> bf16 y). grid=rows, block=128.
// ---------------------------------------------------------------------------
__global__ __launch_bounds__(128) void ln_kernel(const void* __restrict__ x, size_t xoff,
                                                 const void* __restrict__ g,
                                                 const void* __restrict__ b,
                                                 bf16* __restrict__ y, const unsigned* det)
{
    const bool f = det_f32(det);
    int row = blockIdx.x, tid = threadIdx.x;
    float fv[8], s = 0.f, sq = 0.f;
    if (f) {
        const float* xp = (const float*)x + xoff + (size_t)row * 1024 + tid * 8;
        float4 a = *(const float4*)xp;
        float4 c = *(const float4*)(xp + 4);
        fv[0] = a.x; fv[1] = a.y; fv[2] = a.z; fv[3] = a.w;
        fv[4] = c.x; fv[5] = c.y; fv[6] = c.z; fv[7] = c.w;
    } else {
        bf16x8 xv = *(const bf16x8*)((const bf16*)x + xoff + (size_t)row * 1024 + tid * 8);
        #pragma unroll
        for (int j = 0; j < 8; ++j) fv[j] = (float)xv[j];
    }
    #pragma unroll
    for (int j = 0; j < 8; ++j) { s += fv[j]; sq += fv[j] * fv[j]; }
    #pragma unroll
    for (int d = 1; d < 64; d <<= 1) { s += __shfl_xor(s, d, 64); sq += __shfl_xor(sq, d, 64); }
    __shared__ float ss[2], sq2[2];
    int w = tid >> 6;
    if ((tid & 63) == 0) { ss[w] = s; sq2[w] = sq; }
    __syncthreads();
    s = ss[0] + ss[1]; sq = sq2[0] + sq2[1];
    float mean = s * (1.f / 1024.f);
    float var  = sq * (1.f / 1024.f) - mean * mean;
    float rstd = rsqrtf(var + 1e-5f);
    bf16x8 o;
    #pragma unroll
    for (int j = 0; j < 8; ++j)
        o[j] = (bf16)((fv[j] - mean) * rstd * ldx(g, tid * 8 + j, f) + ldx(b, tid * 8 + j, f));
    *(bf16x8*)(y + (size_t)row * 1024 + tid * 8) = o;
}

// ---------------------------------------------------------------------------
// OLD 128x128 GEMM, kept ONLY for EPI 3 (per-head transposed V write).
// ---------------------------------------------------------------------------
template <int EPI>
__global__ __launch_bounds__(256) void gemm_bt(const bf16* __restrict__ A,
                                               const bf16* __restrict__ BT,
                                               void* __restrict__ Cp, size_t coff,
                                               const void* __restrict__ bias, size_t boff,
                                               const void* __restrict__ resid, size_t roff,
                                               const void* __restrict__ coeffs, int ciR, int ciV,
                                               int M, int N, int K, const unsigned* det)
{
    const bool f = det_f32(det);
    __shared__ alignas(16) bf16 smem[17408];   // As(8192) + Bs(8192); EPI3 reuses as 128x136
    bf16* As = smem;
    bf16* Bs = smem + 8192;
    const int tid  = threadIdx.x;
    const int lane = tid & 63;
    const int w    = tid >> 6;
    const int wm   = w >> 1, wn = w & 1;
    const int quad = lane >> 4, l16 = lane & 15;
    const int bm = blockIdx.x * 128, bn = blockIdx.y * 128;

    f32x4 acc[4][4] = {};

    for (int k0 = 0; k0 < K; k0 += 64) {
        #pragma unroll
        for (int i = 0; i < 4; ++i) {
            int u = i * 256 + tid;
            int r = u >> 3, c = (u & 7) * 8;
            __builtin_amdgcn_global_load_lds((gc_ptr)(A + (size_t)(bm + r) * K + k0 + c),
                                             (ls_ptr)(As + (size_t)(i * 256 + (tid & 192)) * 8),
                                             16, 0, 0);
        }
        #pragma unroll
        for (int i = 0; i < 4; ++i) {
            int u = i * 256 + tid;
            int r = u >> 3, c = (u & 7) * 8;
            __builtin_amdgcn_global_load_lds((gc_ptr)(BT + (size_t)(bn + r) * K + k0 + c),
                                             (ls_ptr)(Bs + (size_t)(i * 256 + (tid & 192)) * 8),
                                             16, 0, 0);
        }
        __syncthreads();
        #pragma unroll
        for (int kk = 0; kk < 2; ++kk) {
            bf16x8 af[4], bfr[4];
            #pragma unroll
            for (int i = 0; i < 4; ++i)
                af[i] = *(const bf16x8*)(As + (wm * 64 + i * 16 + l16) * 64 + kk * 32 + quad * 8);
            #pragma unroll
            for (int i = 0; i < 4; ++i)
                bfr[i] = *(const bf16x8*)(Bs + (wn * 64 + i * 16 + l16) * 64 + kk * 32 + quad * 8);
            #pragma unroll
            for (int im = 0; im < 4; ++im)
                #pragma unroll
                for (int in = 0; in < 4; ++in)
                    acc[im][in] = MFMA16(af[im], bfr[in], acc[im][in]);
        }
        __syncthreads();
    }

    if (EPI == 3) {
        // transpose through LDS: T[dk][n], stride 136 (16B-aligned rows)
        bf16* T = smem;
        #pragma unroll
        for (int in = 0; in < 4; ++in) {
            int dk = wn * 64 + in * 16 + l16;
            float bv = ldx(bias, boff + bn + dk, f);
            #pragma unroll
            for (int im = 0; im < 4; ++im)
                #pragma unroll
                for (int r = 0; r < 4; ++r) {
                    int n = wm * 64 + im * 16 + quad * 4 + r;
                    T[dk * 136 + n] = (bf16)(acc[im][in][r] + bv);
                }
        }
        __syncthreads();
        int bq = bm >> 8, n0 = bm & 255, h = bn >> 7;
        bf16* dst = (bf16*)Cp + ((size_t)(bq * 8 + h) * 128) * 256 + n0;
        #pragma unroll
        for (int it = 0; it < 8; ++it) {
            int idx = it * 256 + tid;
            int dk = idx >> 4, ch = idx & 15;
            *(bf16x8*)(dst + (size_t)dk * 256 + ch * 8) = *(const bf16x8*)(T + dk * 136 + ch * 8);
        }
        return;
    }

    float cR = 0.f, cV = 0.f;
    if (EPI == 2) { cR = ldx(coeffs, ciR, f); cV = ldx(coeffs, ciV, f); }
    #pragma unroll
    for (int in = 0; in < 4; ++in) {
        int col = bn + wn * 64 + in * 16 + l16;
        float bv = ldx(bias, boff + col, f);
        #pragma unroll
        for (int im = 0; im < 4; ++im) {
            #pragma unroll
            for (int r = 0; r < 4; ++r) {
                int row = bm + wm * 64 + im * 16 + quad * 4 + r;
                float v = acc[im][in][r] + bv;
                if (EPI == 1) v = 0.5f * v * (1.f + erff(v * 0.7071067811865476f));
                size_t o = coff + (size_t)row * N + col;
                if (EPI == 2) {
                    v = cR * ldx(resid, roff + (size_t)row * N + col, f) + cV * v;
                    if (f) ((float*)Cp)[o] = v; else ((bf16*)Cp)[o] = (bf16)v;
                } else {
                    ((bf16*)Cp)[o] = (bf16)v;
                }
            }
        }
    }
}

// ---------------------------------------------------------------------------
// 256x256-tile GEMM, 4-phase K-loop (R3): compiler-managed counted lgkmcnt
// (no manual lgkmcnt(0) wait-all), kk-outer independent MFMA clusters,
// 4 barriers + 1 counted vmcnt per K-tile. T2 swizzle + XCD-chunk map +
// LDS-staged vectorized epilogue unchanged from R2.
// Hazard schedule (tile T, buffer P=T&1):
//   pha: read af-lo(T)+bf-lo(T) [12]; stage A-hi(T+1)->~P;  MFMA Q(0,0)
//   phb: read bf-hi(T) [4];          stage A-lo(T+2)->P;   MFMA Q(0,1)
//   phc: read af-hi(T) [8];          stage B-lo(T+2)->P;   MFMA Q(1,0); vmcnt(4)
//   phd:                             stage B-hi(T+2)->P;   MFMA Q(1,1)
// WAR: each stage issues >=1 barrier after its region's consuming MFMA.
// RAW: vmcnt(4)@phc(T) covers through T.pha => af-hi(T+1) ready for phc(T+1);
//      older stages (A-lo/B-lo/B-hi) covered a fortiori. Tail: vmcnt(0).
// ---------------------------------------------------------------------------
template <int BS>
__device__ __forceinline__ void stage_h(const bf16* __restrict__ src, int Kd, bf16* dst,
                                        int h, int tid, size_t base)
{
    const int msk = (1 << BS) - 1;
    #pragma unroll
    for (int j = 0; j < 2; ++j) {
        int rl  = j * 64 + (tid >> 3);                                   // logical row 0..127
        int rp  = (rl & msk) + ((rl >> BS) << (BS + 1)) + (h << BS);     // physical row 0..255
        int rl0 = j * 64 + ((tid & 448) >> 3);                           // wave-uniform first row
        int rp0 = (rl0 & msk) + ((rl0 >> BS) << (BS + 1)) + (h << BS);
        int cs  = ((tid & 7) ^ ((tid >> 3) & 7)) << 3;                   // pre-swizzled source col
        __builtin_amdgcn_global_load_lds((gc_ptr)(src + base + (size_t)rp * Kd + cs),
                                         (ls_ptr)(dst + rp0 * 64), 16, 0, 0);
    }
}

#define BARR() asm volatile("s_barrier" ::: "memory")
#define SP1()  __builtin_amdgcn_s_setprio(1)
#define SP0()  __builtin_amdgcn_s_setprio(0)

#define LD_AF(AB, MH)                                                                   \
    _Pragma("unroll") for (int m_ = 0; m_ < 4; ++m_)                                    \
    _Pragma("unroll") for (int kk_ = 0; kk_ < 2; ++kk_)                                 \
        af[m_][kk_] = *(const bf16x8*)((AB) + (wm * 128 + (MH) * 64 + m_ * 16 + l16) * 64 \
                                       + ((kk_ * 32 + quad * 8) ^ swzc));

#define LD_BL(BB)                                                                       \
    _Pragma("unroll") for (int n_ = 0; n_ < 2; ++n_)                                    \
    _Pragma("unroll") for (int kk_ = 0; kk_ < 2; ++kk_)                                 \
        bl[n_][kk_] = *(const bf16x8*)((BB) + (wn * 64 + n_ * 16 + l16) * 64            \
                                       + ((kk_ * 32 + quad * 8) ^ swzc));

#define LD_BH(BB)                                                                       \
    _Pragma("unroll") for (int n_ = 0; n_ < 2; ++n_)                                    \
    _Pragma("unroll") for (int kk_ = 0; kk_ < 2; ++kk_)                                 \
        bh[n_][kk_] = *(const bf16x8*)((BB) + (wn * 64 + 32 + n_ * 16 + l16) * 64       \
                                       + ((kk_ * 32 + quad * 8) ^ swzc));

// kk OUTER: all 8 MFMAs of a kk-pass are independent (no dependent pairs).
#define MMQ(MH, NH, BF)                                                                 \
    _Pragma("unroll") for (int kk_ = 0; kk_ < 2; ++kk_)                                 \
    _Pragma("unroll") for (int m_ = 0; m_ < 4; ++m_)                                    \
    _Pragma("unroll") for (int n_ = 0; n_ < 2; ++n_)                                    \
        acc[(MH) * 4 + m_][(NH) * 2 + n_] =                                             \
            MFMA16(af[m_][kk_], BF[n_][kk_], acc[(MH) * 4 + m_][(NH) * 2 + n_]);

#define KTILE(P, T)                                                                     \
    {                                                                                   \
        const bf16* Ab = smem + (P) * 32768;                                            \
        const bf16* Bb = smem + (P) * 32768 + 16384;                                    \
        bf16* An = smem + (1 - (P)) * 32768;                                            \
        bf16* Ac = smem + (P) * 32768;                                                  \
        bf16* Bc = smem + (P) * 32768 + 16384;                                          \
        /* pha */                                                                       \
        LD_BL(Bb)                                                                       \
        LD_AF(Ab, 0)                                                                    \
        if ((T) + 1 < NT) stage_h<6>(A, K, An, 1, tid, Arow + (size_t)((T) + 1) * 64);  \
        SP1(); MMQ(0, 0, bl) SP0();                                                     \
        BARR();                                                                         \
        /* phb */                                                                       \
        LD_BH(Bb)                                                                       \
        if ((T) + 2 < NT) stage_h<6>(A, K, Ac, 0, tid, Arow + (size_t)((T) + 2) * 64);  \
        SP1(); MMQ(0, 1, bh) SP0();                                                     \
        BARR();                                                                         \
        /* phc */                                                                       \
        LD_AF(Ab, 1)                                                                    \
        if ((T) + 2 < NT) stage_h<5>(BT, K, Bc, 0, tid, Brow + (size_t)((T) + 2) * 64); \
        SP1(); MMQ(1, 0, bl) SP0();                                                     \
        if ((T) + 2 < NT) { asm volatile("s_waitcnt vmcnt(4)" ::: "memory"); }          \
        else              { asm volatile("s_waitcnt vmcnt(0)" ::: "memory"); }          \
        BARR();                                                                         \
        /* phd */                                                                       \
        if ((T) + 2 < NT) stage_h<5>(BT, K, Bc, 1, tid, Brow + (size_t)((T) + 2) * 64); \
        SP1(); MMQ(1, 1, bh) SP0();                                                     \
        BARR();                                                                         \
    }

template <int EPI>
__global__ __launch_bounds__(512, 2) void gemm256(const bf16* __restrict__ A,
                                                  const bf16* __restrict__ BT,
                                                  void* __restrict__ Cp, size_t coff,
                                                  const void* __restrict__ bias, size_t boff,
                                                  const void* __restrict__ resid, size_t roff,
                                                  const void* __restrict__ coeffs, int ciR, int ciV,
                                                  int M, int N, int K, const unsigned* det)
{
    const bool f = det_f32(det);
    __shared__ alignas(16) bf16 smem[65536];   // 128 KiB: 2 x (A 16384 + B 16384) elems

    // Per-XCD contiguous-bx chunk mapping (nbx = M/256 = 64): xcd owns 8 bx for
    // all by -> A fetched ~once chip-wide (R2-verified: FETCH = A + 8x B).
    const int bid = blockIdx.x;
    const int xcd = bid & 7, ch = bid >> 3;
    const int bx = xcd * 8 + (ch & 7);
    const int by = ch >> 3;
    const int bm = bx << 8, bn = by << 8;

    const int tid  = threadIdx.x;
    const int lane = tid & 63, w = tid >> 6;
    const int wm = w >> 2, wn = w & 3;
    const int quad = lane >> 4, l16 = lane & 15;
    const int swzc = (l16 & 7) << 3;

    const int NT = K >> 6;
    const size_t Arow = (size_t)bm * K;
    const size_t Brow = (size_t)bn * K;

    f32x4 acc[8][4] = {};
    bf16x8 af[4][2], bl[2][2], bh[2][2];

    // prologue: tile0 (4 halves) + tile1 (A-lo, B-lo, B-hi) -> 14 loads, keep 6 in flight
    stage_h<6>(A,  K, smem,         0, tid, Arow);
    stage_h<6>(A,  K, smem,         1, tid, Arow);
    stage_h<5>(BT, K, smem + 16384, 0, tid, Brow);
    stage_h<5>(BT, K, smem + 16384, 1, tid, Brow);
    stage_h<6>(A,  K, smem + 32768, 0, tid, Arow + 64);
    stage_h<5>(BT, K, smem + 49152, 0, tid, Brow + 64);
    stage_h<5>(BT, K, smem + 49152, 1, tid, Brow + 64);
    asm volatile("s_waitcnt vmcnt(6)" ::: "memory");
    BARR();

    for (int t = 0; t < NT; t += 2) {   // NT even for all our shapes (16 or 64)
        KTILE(0, t)
        KTILE(1, t + 1)
    }

    // ---- LDS-staged vectorized epilogue (unchanged from R2) ----
    __syncthreads();
    float cR = 0.f, cV = 0.f;
    if (EPI == 2) { cR = ldx(coeffs, ciR, f); cV = ldx(coeffs, ciV, f); }

    if (EPI == 2 && f) {
        // fp32 out with fp32 resid: 4 passes of 64 rows, stride 264 f32.
        float* T = (float*)smem;
        for (int p = 0; p < 4; ++p) {
            if (wm == (p >> 1)) {
                const int mh = p & 1;
                #pragma unroll
                for (int n = 0; n < 4; ++n) {
                    float bv = ldx(bias, boff + bn + wn * 64 + n * 16 + l16, f);
                    #pragma unroll
                    for (int m2 = 0; m2 < 4; ++m2) {
                        #pragma unroll
                        for (int r = 0; r < 4; ++r)
                            T[(m2 * 16 + quad * 4 + r) * 264 + wn * 64 + n * 16 + l16] =
                                acc[mh * 4 + m2][n][r] + bv;
                    }
                }
            }
            __syncthreads();
            #pragma unroll
            for (int i = 0; i < 8; ++i) {
                int u = i * 512 + tid;                 // 0..4095
                int lr = u >> 6, c = (u & 63) * 4;     // 64 rows x 64 float4 chunks
                int row = bm + p * 64 + lr;
                size_t o = coff + (size_t)row * N + bn + c;
                float4 rv = *(const float4*)((const float*)resid + roff + (size_t)row * N + bn + c);
                float4 tv = *(const float4*)(T + lr * 264 + c);
                float4 ov;
                ov.x = cR * rv.x + cV * tv.x;
                ov.y = cR * rv.y + cV * tv.y;
                ov.z = cR * rv.z + cV * tv.z;
                ov.w = cR * rv.w + cV * tv.w;
                *(float4*)((float*)Cp + o) = ov;
            }
            __syncthreads();
        }
    } else {
        // bf16 out (EPI 0/1, or EPI2 with bf16 resid): 2 passes of 128 rows, stride 272 bf16.
        bf16* T = smem;
        for (int p = 0; p < 2; ++p) {
            if (wm == p) {
                #pragma unroll
                for (int n = 0; n < 4; ++n) {
                    float bv = ldx(bias, boff + bn + wn * 64 + n * 16 + l16, f);
                    #pragma unroll
                    for (int m = 0; m < 8; ++m) {
                        #pragma unroll
                        for (int r = 0; r < 4; ++r) {
                            float v = acc[m][n][r] + bv;
                            if (EPI == 1) v = 0.5f * v * (1.f + erff(v * 0.7071067811865476f));
                            T[(m * 16 + quad * 4 + r) * 272 + wn * 64 + n * 16 + l16] = (bf16)v;
                        }
                    }
                }
            }
            __syncthreads();
            #pragma unroll
            for (int i = 0; i < 8; ++i) {
                int u = i * 512 + tid;                 // 0..4095
                int lr = u >> 5, c = (u & 31) * 8;     // 128 rows x 32 bf16x8 chunks
                int row = bm + p * 128 + lr;
                bf16x8 tv = *(const bf16x8*)(T + lr * 272 + c);
                if (EPI == 2) {
                    bf16x8 rv = *(const bf16x8*)((const bf16*)resid + roff + (size_t)row * N + bn + c);
                    #pragma unroll
                    for (int j = 0; j < 8; ++j)
                        tv[j] = (bf16)(cR * (float)rv[j] + cV * (float)tv[j]);
                }
                *(bf16x8*)((bf16*)Cp + coff + (size_t)row * N + bn + c) = tv;
            }
            __syncthreads();
        }
    }
}

// ---------------------------------------------------------------------------
// Cross-attention, one stream: grid 2048 = 64 b x 8 h x 4 row-blocks of 64.
// ---------------------------------------------------------------------------
__global__ __launch_bounds__(256) void attn_kernel(const bf16* __restrict__ Q,
                                                   const bf16* __restrict__ K,
                                                   const bf16* __restrict__ VT,
                                                   bf16* __restrict__ O)
{
    const int bi = blockIdx.x;
    const int mb = bi & 3, h = (bi >> 2) & 7, b = bi >> 5;
    const bf16* Qp = Q + (size_t)b * (256 * 1024) + h * 128;
    const bf16* Kp = K + (size_t)b * (256 * 1024) + h * 128;
    const bf16* Vp = VT + (size_t)(b * 8 + h) * (128 * 256);
    bf16* Op = O + (size_t)b * (256 * 1024) + h * 128;
    const int m0 = mb * 64;

    const int tid = threadIdx.x, lane = tid & 63, w = tid >> 6;
    const int quad = lane >> 4, l16 = lane & 15;

    f32x4 sa[4][4] = {};
    #pragma unroll
    for (int k0 = 0; k0 < 128; k0 += 32) {
        bf16x8 aq[4], bk[4];
        #pragma unroll
        for (int i = 0; i < 4; ++i)
            aq[i] = *(const bf16x8*)(Qp + (size_t)(m0 + i * 16 + l16) * 1024 + k0 + quad * 8);
        #pragma unroll
        for (int i = 0; i < 4; ++i)
            bk[i] = *(const bf16x8*)(Kp + (size_t)(w * 64 + i * 16 + l16) * 1024 + k0 + quad * 8);
        #pragma unroll
        for (int im = 0; im < 4; ++im)
            #pragma unroll
            for (int in = 0; in < 4; ++in)
                sa[im][in] = MFMA16(aq[im], bk[in], sa[im][in]);
    }
    const float scale = 0.088388347648318447f;  // 1/sqrt(128)
    #pragma unroll
    for (int im = 0; im < 4; ++im)
        #pragma unroll
        for (int in = 0; in < 4; ++in)
            #pragma unroll
            for (int r = 0; r < 4; ++r)
                sa[im][in][r] *= scale;

    __shared__ float red1[4][64];
    __shared__ float red2[4][64];
    __shared__ alignas(16) bf16 Ps[64 * 264];

    float rmax[4][4];
    #pragma unroll
    for (int im = 0; im < 4; ++im)
        #pragma unroll
        for (int r = 0; r < 4; ++r) {
            float m = fmaxf(fmaxf(sa[im][0][r], sa[im][1][r]), fmaxf(sa[im][2][r], sa[im][3][r]));
            #pragma unroll
            for (int d = 1; d < 16; d <<= 1) m = fmaxf(m, __shfl_xor(m, d, 64));
            rmax[im][r] = m;
        }
    if (l16 == 0)
        #pragma unroll
        for (int im = 0; im < 4; ++im)
            #pragma unroll
            for (int r = 0; r < 4; ++r)
                red1[w][im * 16 + quad * 4 + r] = rmax[im][r];
    __syncthreads();
    #pragma unroll
    for (int im = 0; im < 4; ++im)
        #pragma unroll
        for (int r = 0; r < 4; ++r) {
            int row = im * 16 + quad * 4 + r;
            rmax[im][r] = fmaxf(fmaxf(red1[0][row], red1[1][row]),
                                fmaxf(red1[2][row], red1[3][row]));
        }

    float rsum[4][4];
    #pragma unroll
    for (int im = 0; im < 4; ++im)
        #pragma unroll
        for (int r = 0; r < 4; ++r) {
            float t = 0.f;
            #pragma unroll
            for (int in = 0; in < 4; ++in) {
                float e = __expf(sa[im][in][r] - rmax[im][r]);
                sa[im][in][r] = e;
                t += e;
            }
            #pragma unroll
            for (int d = 1; d < 16; d <<= 1) t += __shfl_xor(t, d, 64);
            rsum[im][r] = t;
        }
    if (l16 == 0)
        #pragma unroll
        for (int im = 0; im < 4; ++im)
            #pragma unroll
            for (int r = 0; r < 4; ++r)
                red2[w][im * 16 + quad * 4 + r] = rsum[im][r];
    __syncthreads();
    #pragma unroll
    for (int im = 0; im < 4; ++im)
        #pragma unroll
        for (int r = 0; r < 4; ++r) {
            int row = im * 16 + quad * 4 + r;
            float inv = 1.f / (red2[0][row] + red2[1][row] + red2[2][row] + red2[3][row]);
            #pragma unroll
            for (int in = 0; in < 4; ++in)
                Ps[row * 264 + w * 64 + in * 16 + l16] = (bf16)(sa[im][in][r] * inv);
        }
    __syncthreads();

    f32x4 oa[4][2] = {};
    #pragma unroll
    for (int k0 = 0; k0 < 256; k0 += 32) {
        bf16x8 ap[4], bv[2];
        #pragma unroll
        for (int im = 0; im < 4; ++im)
            ap[im] = *(const bf16x8*)(Ps + (im * 16 + l16) * 264 + k0 + quad * 8);
        #pragma unroll
        for (int in = 0; in < 2; ++in)
            bv[in] = *(const bf16x8*)(Vp + (size_t)(w * 32 + in * 16 + l16) * 256 + k0 + quad * 8);
        #pragma unroll
        for (int im = 0; im < 4; ++im)
            #pragma unroll
            for (int in = 0; in < 2; ++in)
                oa[im][in] = MFMA16(ap[im], bv[in], oa[im][in]);
    }
    #pragma unroll
    for (int im = 0; im < 4; ++im)
        #pragma unroll
        for (int in = 0; in < 2; ++in)
            #pragma unroll
            for (int r = 0; r < 4; ++r) {
                int row = m0 + im * 16 + quad * 4 + r;
                int col = w * 32 + in * 16 + l16;
                Op[(size_t)row * 1024 + col] = (bf16)oa[im][in][r];
            }
}

// ---------------------------------------------------------------------------
extern "C" void kernel_launch(void* const* d_in, const int* in_sizes, int n_in,
                              void* d_out, int out_size, void* d_ws, size_t ws_size,
                              hipStream_t stream)
{
    const void* rgb    = d_in[0];
    const void* ir     = d_in[1];
    const void* ln1_g  = d_in[2];
    const void* ln1_b  = d_in[3];
    const void* ln2_g  = d_in[4];
    const void* ln2_b  = d_in[5];
    const void* Wqkv_v = d_in[6];
    const void* bqkv_v = d_in[7];
    const void* Wqkv_i = d_in[8];
    const void* bqkv_i = d_in[9];
    const void* Wo_v   = d_in[10];
    const void* bo_v   = d_in[11];
    const void* Wo_i   = d_in[12];
    const void* bo_i   = d_in[13];
    const void* bln_g  = d_in[14];
    const void* bln_b  = d_in[15];
    const void* W1_v   = d_in[16];
    const void* b1_v   = d_in[17];
    const void* W2_v   = d_in[18];
    const void* b2_v   = d_in[19];
    const void* W1_i   = d_in[20];
    const void* b1_i   = d_in[21];
    const void* W2_i   = d_in[22];
    const void* b2_i   = d_in[23];
    const void* coeffs = d_in[24];
    const unsigned* det = (const unsigned*)ln1_g;

    // workspace layout (bytes), peak 272,629,760 (~260 MiB)
    char* ws = (char*)d_ws;
    bf16* wtq_v  = (bf16*)(ws + 0);            // 6 MiB (3x 1024x1024)
    bf16* wtq_i  = (bf16*)(ws + 6291456);
    bf16* wto_v  = (bf16*)(ws + 12582912);     // 2 MiB
    bf16* wto_i  = (bf16*)(ws + 14680064);
    bf16* wt1_v  = (bf16*)(ws + 16777216);     // 8 MiB (4096x1024)
    bf16* wt1_i  = (bf16*)(ws + 25165824);
    bf16* wt2_v  = (bf16*)(ws + 33554432);     // 8 MiB (1024x4096)
    bf16* wt2_i  = (bf16*)(ws + 41943040);
    bf16* lnbuf  = (bf16*)(ws + 50331648);     // 32 MiB; reused as att_i
    bf16* q_v    = (bf16*)(ws + 83886080);     // 32 MiB; reused as att_v, then Hbuf
    bf16* k_v    = (bf16*)(ws + 117440512);
    bf16* vt_v   = (bf16*)(ws + 150994944);
    bf16* q_i    = (bf16*)(ws + 184549376);
    bf16* k_i    = (bf16*)(ws + 218103808);    // reused as mlp_ln
    bf16* vt_i   = (bf16*)(ws + 251658240);    // ends 285212672
    bf16* att_i  = lnbuf;
    bf16* att_v  = q_v;
    bf16* Hbuf   = (bf16*)(ws + 83886080);     // 128 MiB (16384x4096)
    bf16* mlp_ln = (bf16*)(ws + 218103808);

    dim3 tb(32, 8);
    // ---- weight transposes (external dtype -> bf16 N x K)
    for (int t = 0; t < 3; ++t) {
        transpose2d<<<dim3(32, 32), tb, 0, stream>>>(Wqkv_v, (size_t)t * 1048576, wtq_v + (size_t)t * 1048576, 1024, 1024, det);
        transpose2d<<<dim3(32, 32), tb, 0, stream>>>(Wqkv_i, (size_t)t * 1048576, wtq_i + (size_t)t * 1048576, 1024, 1024, det);
    }
    transpose2d<<<dim3(32, 32),  tb, 0, stream>>>(Wo_v, 0, wto_v, 1024, 1024, det);
    transpose2d<<<dim3(32, 32),  tb, 0, stream>>>(Wo_i, 0, wto_i, 1024, 1024, det);
    transpose2d<<<dim3(128, 32), tb, 0, stream>>>(W1_v, 0, wt1_v, 1024, 4096, det);
    transpose2d<<<dim3(128, 32), tb, 0, stream>>>(W1_i, 0, wt1_i, 1024, 4096, det);
    transpose2d<<<dim3(32, 128), tb, 0, stream>>>(W2_v, 0, wt2_v, 4096, 1024, det);
    transpose2d<<<dim3(32, 128), tb, 0, stream>>>(W2_i, 0, wt2_i, 4096, 1024, det);

    // ---- LN + QKV (Q,K via 256^2 4-phase; V via old EPI3 per-head transpose)
    ln_kernel<<<16384, 128, 0, stream>>>(rgb, 0, ln1_g, ln1_b, lnbuf, det);
    gemm256<0><<<256, 512, 0, stream>>>(lnbuf, wtq_v + 0 * 1048576, q_v, 0, bqkv_v, 0,    nullptr, 0, nullptr, 0, 0, 16384, 1024, 1024, det);
    gemm256<0><<<256, 512, 0, stream>>>(lnbuf, wtq_v + 1 * 1048576, k_v, 0, bqkv_v, 1024, nullptr, 0, nullptr, 0, 0, 16384, 1024, 1024, det);
    gemm_bt<3><<<dim3(128, 8), 256, 0, stream>>>(lnbuf, wtq_v + 2 * 1048576, vt_v, 0, bqkv_v, 2048, nullptr, 0, nullptr, 0, 0, 16384, 1024, 1024, det);
    ln_kernel<<<16384, 128, 0, stream>>>(ir, 0, ln2_g, ln2_b, lnbuf, det);
    gemm256<0><<<256, 512, 0, stream>>>(lnbuf, wtq_i + 0 * 1048576, q_i, 0, bqkv_i, 0,    nullptr, 0, nullptr, 0, 0, 16384, 1024, 1024, det);
    gemm256<0><<<256, 512, 0, stream>>>(lnbuf, wtq_i + 1 * 1048576, k_i, 0, bqkv_i, 1024, nullptr, 0, nullptr, 0, 0, 16384, 1024, 1024, det);
    gemm_bt<3><<<dim3(128, 8), 256, 0, stream>>>(lnbuf, wtq_i + 2 * 1048576, vt_i, 0, bqkv_i, 2048, nullptr, 0, nullptr, 0, 0, 16384, 1024, 1024, det);

    // ---- attention: ir-side first (frees q_v), then vis-side
    attn_kernel<<<2048, 256, 0, stream>>>(q_v, k_i, vt_i, att_i);   // att_ir  (overlays lnbuf)
    attn_kernel<<<2048, 256, 0, stream>>>(q_i, k_v, vt_v, att_v);   // att_vis (overlays q_v)

    // ---- output projection + residual blend -> d_out
    gemm256<2><<<256, 512, 0, stream>>>(att_v, wto_v, d_out, 0,        bo_v, 0, rgb, 0, coeffs, 0, 1, 16384, 1024, 1024, det);
    gemm256<2><<<256, 512, 0, stream>>>(att_i, wto_i, d_out, 16777216, bo_i, 0, ir,  0, coeffs, 2, 3, 16384, 1024, 1024, det);

    // ---- MLP vis: LN -> W1+gelu -> W2 + blend (in-place on d_out[0])
    ln_kernel<<<16384, 128, 0, stream>>>(d_out, 0, bln_g, bln_b, mlp_ln, det);
    gemm256<1><<<1024, 512, 0, stream>>>(mlp_ln, wt1_v, Hbuf, 0, b1_v, 0, nullptr, 0, nullptr, 0, 0, 16384, 4096, 1024, det);
    gemm256<2><<<256,  512, 0, stream>>>(Hbuf, wt2_v, d_out, 0, b2_v, 0, d_out, 0, coeffs, 4, 5, 16384, 1024, 4096, det);

    // ---- MLP ir
    ln_kernel<<<16384, 128, 0, stream>>>(d_out, 16777216, bln_g, bln_b, mlp_ln, det);
    gemm256<1><<<1024, 512, 0, stream>>>(mlp_ln, wt1_i, Hbuf, 0, b1_i, 0, nullptr, 0, nullptr, 0, 0, 16384, 4096, 1024, det);
    gemm256<2><<<256,  512, 0, stream>>>(Hbuf, wt2_i, d_out, 16777216, b2_i, 0, d_out, 16777216, coeffs, 6, 7, 16384, 1024, 4096, det);
}